// Round 1
// baseline (860.104 us; speedup 1.0000x reference)
//
#include <hip/hip_runtime.h>
#include <math.h>

#define CIN 128
#define COUT 64

// deg[i] = 1.0 (self loop), inv[i] = -1
__global__ __launch_bounds__(256) void k_init(float* __restrict__ deg, int* __restrict__ inv, int N) {
    int i = blockIdx.x * 256 + threadIdx.x;
    if (i < N) { deg[i] = 1.0f; inv[i] = -1; }
}

// inv[unpool_mask[i]] = i
__global__ __launch_bounds__(256) void k_mask(const int* __restrict__ mask, int* __restrict__ inv, int M) {
    int i = blockIdx.x * 256 + threadIdx.x;
    if (i < M) inv[mask[i]] = i;
}

// deg[dst] += 1 for every directed edge
__global__ __launch_bounds__(256) void k_deg(const int* __restrict__ dst, float* __restrict__ deg, int E) {
    int i = blockIdx.x * 256 + threadIdx.x;
    if (i < E) atomicAdd(&deg[dst[i]], 1.0f);
}

// h[M,64] = x[M,128] @ W[128,64]  (fp32, LDS-tiled, 64 rows/block)
__global__ __launch_bounds__(256) void k_gemm(const float* __restrict__ x, const float* __restrict__ W,
                                              float* __restrict__ h, int M) {
    __shared__ float sW[CIN * COUT];   // [k][c] 32 KB
    __shared__ float sX[64 * CIN];     // [r][k] 32 KB
    int t = threadIdx.x;
    int row0 = blockIdx.x * 64;
    for (int i = t; i < CIN * COUT; i += 256) sW[i] = W[i];
    for (int i = t; i < 64 * CIN; i += 256) {
        int r = i >> 7, k = i & (CIN - 1);
        int gr = row0 + r;
        sX[i] = (gr < M) ? x[(size_t)gr * CIN + k] : 0.0f;
    }
    __syncthreads();
    int col = t & 63;       // lane = output channel
    int rg  = t >> 6;       // wave id -> row group (16 rows)
    float acc[16];
#pragma unroll
    for (int i = 0; i < 16; ++i) acc[i] = 0.0f;
    for (int k = 0; k < CIN; k += 4) {
        float w0 = sW[(k + 0) * COUT + col];
        float w1 = sW[(k + 1) * COUT + col];
        float w2 = sW[(k + 2) * COUT + col];
        float w3 = sW[(k + 3) * COUT + col];
#pragma unroll
        for (int i = 0; i < 16; ++i) {
            const float4 a = *reinterpret_cast<const float4*>(&sX[(rg * 16 + i) * CIN + k]);
            acc[i] = fmaf(a.x, w0, acc[i]);
            acc[i] = fmaf(a.y, w1, acc[i]);
            acc[i] = fmaf(a.z, w2, acc[i]);
            acc[i] = fmaf(a.w, w3, acc[i]);
        }
    }
#pragma unroll
    for (int i = 0; i < 16; ++i) {
        int gr = row0 + rg * 16 + i;
        if (gr < M) h[(size_t)gr * COUT + col] = acc[i];
    }
}

// out[f][:] = (inv[f]>=0) ? h[inv[f]][:] / deg[f] : 0      (also zero-inits d_out)
__global__ __launch_bounds__(256) void k_self(const float* __restrict__ h, const int* __restrict__ inv,
                                              const float* __restrict__ deg, float* __restrict__ out, int N) {
    int tid = blockIdx.x * 256 + threadIdx.x;   // over N*16 float4s
    if (tid >= N * 16) return;
    int f = tid >> 4, q = tid & 15;
    int r = inv[f];
    float4 v = make_float4(0.f, 0.f, 0.f, 0.f);
    if (r >= 0) {
        v = reinterpret_cast<const float4*>(h)[r * 16 + q];
        float s = 1.0f / deg[f];
        v.x *= s; v.y *= s; v.z *= s; v.w *= s;
    }
    reinterpret_cast<float4*>(out)[tid] = v;
}

// for each edge with coarse src: out[dst][:] += h[inv[src]][:] * rsqrt(deg[src]*deg[dst])
__global__ __launch_bounds__(256) void k_edge(const int* __restrict__ src, const int* __restrict__ dst,
                                              const int* __restrict__ inv, const float* __restrict__ deg,
                                              const float* __restrict__ h, float* __restrict__ out, int E) {
    int wid  = (blockIdx.x * 256 + threadIdx.x) >> 6;  // global wave id
    int lane = threadIdx.x & 63;
    int nw   = gridDim.x * 4;
    for (int e = wid; e < E; e += nw) {
        int s = src[e];
        int r = inv[s];
        if (r < 0) continue;                 // src has no feature -> contributes nothing
        int d = dst[e];
        float coef = rsqrtf(deg[s] * deg[d]);
        atomicAdd(&out[(size_t)d * COUT + lane], h[(size_t)r * COUT + lane] * coef);
    }
}

// out = elu(out + b)
__global__ __launch_bounds__(256) void k_elu(float* __restrict__ out, const float* __restrict__ b, int N16) {
    int tid = blockIdx.x * 256 + threadIdx.x;
    if (tid >= N16) return;
    int q = tid & 15;
    float4 v = reinterpret_cast<float4*>(out)[tid];
    float4 bb = reinterpret_cast<const float4*>(b)[q];
    v.x += bb.x; v.y += bb.y; v.z += bb.z; v.w += bb.w;
    v.x = v.x > 0.f ? v.x : expm1f(v.x);
    v.y = v.y > 0.f ? v.y : expm1f(v.y);
    v.z = v.z > 0.f ? v.z : expm1f(v.z);
    v.w = v.w > 0.f ? v.w : expm1f(v.w);
    reinterpret_cast<float4*>(out)[tid] = v;
}

extern "C" void kernel_launch(void* const* d_in, const int* in_sizes, int n_in,
                              void* d_out, int out_size, void* d_ws, size_t ws_size,
                              hipStream_t stream) {
    const float* x    = (const float*)d_in[0];
    const float* W    = (const float*)d_in[1];
    const float* b    = (const float*)d_in[2];
    const int*   edge = (const int*)d_in[3];
    const int*   mask = (const int*)d_in[4];
    const int Mx = in_sizes[0] / CIN;     // 163968 coarse rows
    const int E  = in_sizes[3] / 2;       // 3932160 edges
    const int N  = out_size / COUT;       // 655360 fine nodes

    const int* src = edge;
    const int* dst = edge + E;

    float* deg = (float*)d_ws;                                  // N floats
    int*   inv = (int*)((char*)d_ws + (size_t)N * 4);           // N ints
    float* h   = (float*)((char*)d_ws + (size_t)N * 8);         // Mx*64 floats
    float* out = (float*)d_out;

    k_init<<<(N + 255) / 256, 256, 0, stream>>>(deg, inv, N);
    k_mask<<<(Mx + 255) / 256, 256, 0, stream>>>(mask, inv, Mx);
    k_deg <<<(E + 255) / 256, 256, 0, stream>>>(dst, deg, E);
    k_gemm<<<(Mx + 63) / 64, 256, 0, stream>>>(x, W, h, Mx);
    k_self<<<((size_t)N * 16 + 255) / 256, 256, 0, stream>>>(h, inv, deg, out, N);
    k_edge<<<8192, 256, 0, stream>>>(src, dst, inv, deg, h, out, E);
    k_elu <<<((size_t)N * 16 + 255) / 256, 256, 0, stream>>>(out, b, N * 16);
}

// Round 2
// 616.693 us; speedup vs baseline: 1.3947x; 1.3947x over previous
//
#include <hip/hip_runtime.h>
#include <math.h>

#define CIN 128
#define COUT 64
#define SCAN_CHUNK 4096

// cnt[i] = 0, inv[i] = -1
__global__ __launch_bounds__(256) void k_init(int* __restrict__ cnt, int* __restrict__ inv, int N) {
    int i = blockIdx.x * 256 + threadIdx.x;
    if (i < N) { cnt[i] = 0; inv[i] = -1; }
}

// inv[unpool_mask[i]] = i
__global__ __launch_bounds__(256) void k_mask(const int* __restrict__ mask, int* __restrict__ inv, int M) {
    int i = blockIdx.x * 256 + threadIdx.x;
    if (i < M) inv[mask[i]] = i;
}

// packed histogram: low 16 bits = total in-degree (for deg), high 16 = coarse-src in-degree (for CSR)
__global__ __launch_bounds__(256) void k_count(const int* __restrict__ src, const int* __restrict__ dst,
                                               const int* __restrict__ inv, int* __restrict__ cnt, int E) {
    int i = blockIdx.x * 256 + threadIdx.x;
    if (i >= E) return;
    int s = src[i];
    int add = 1 + ((inv[s] >= 0) ? 65536 : 0);
    atomicAdd(&cnt[dst[i]], add);
}

// ---- exclusive scan of (cnt[i]>>16) over N elements ----
__global__ __launch_bounds__(256) void k_scan1(const int* __restrict__ cnt, int* __restrict__ bsum, int N) {
    __shared__ int sm[256];
    int t = threadIdx.x;
    int base = blockIdx.x * SCAN_CHUNK + t * 16;
    int s = 0;
#pragma unroll
    for (int j = 0; j < 16; ++j) { int idx = base + j; if (idx < N) s += (cnt[idx] >> 16); }
    sm[t] = s; __syncthreads();
    for (int off = 128; off > 0; off >>= 1) { if (t < off) sm[t] += sm[t + off]; __syncthreads(); }
    if (t == 0) bsum[blockIdx.x] = sm[0];
}

__global__ void k_scan2(int* __restrict__ bsum, int nb) {
    if (threadIdx.x == 0 && blockIdx.x == 0) {
        int run = 0;
        for (int i = 0; i < nb; ++i) { int v = bsum[i]; bsum[i] = run; run += v; }
    }
}

__global__ __launch_bounds__(256) void k_scan3(const int* __restrict__ cnt, const int* __restrict__ bsum,
                                               int* __restrict__ offs, int* __restrict__ cursor, int N) {
    __shared__ int sm[256];
    int t = threadIdx.x;
    int base = blockIdx.x * SCAN_CHUNK + t * 16;
    int loc[16];
    int s = 0;
#pragma unroll
    for (int j = 0; j < 16; ++j) {
        int idx = base + j;
        int v = (idx < N) ? (cnt[idx] >> 16) : 0;
        loc[j] = s; s += v;
    }
    sm[t] = s; __syncthreads();
    if (t == 0) {
        int run = bsum[blockIdx.x];
        for (int i = 0; i < 256; ++i) { int v = sm[i]; sm[i] = run; run += v; }
    }
    __syncthreads();
    int tb = sm[t];
#pragma unroll
    for (int j = 0; j < 16; ++j) {
        int idx = base + j;
        if (idx < N) { int o = tb + loc[j]; offs[idx] = o; cursor[idx] = o; }
    }
}

// CSR fill: for each contributing edge write (coarse_row, coef) into dst's segment
__global__ __launch_bounds__(256) void k_fill(const int* __restrict__ src, const int* __restrict__ dst,
                                              const int* __restrict__ inv, const int* __restrict__ cnt,
                                              int* __restrict__ cursor, int2* __restrict__ vals, int E) {
    int i = blockIdx.x * 256 + threadIdx.x;
    if (i >= E) return;
    int s = src[i];
    int r = inv[s];
    if (r < 0) return;
    int d = dst[i];
    float degs = (float)((cnt[s] & 0xFFFF) + 1);
    float degd = (float)((cnt[d] & 0xFFFF) + 1);
    float coef = rsqrtf(degs * degd);
    int pos = atomicAdd(&cursor[d], 1);
    vals[pos] = make_int2(r, __float_as_int(coef));
}

// h[M,64] = x[M,128] @ W[128,64]  (fp32, LDS-tiled, 64 rows/block)
__global__ __launch_bounds__(256) void k_gemm(const float* __restrict__ x, const float* __restrict__ W,
                                              float* __restrict__ h, int M) {
    __shared__ float sW[CIN * COUT];   // [k][c] 32 KB
    __shared__ float sX[64 * CIN];     // [r][k] 32 KB
    int t = threadIdx.x;
    int row0 = blockIdx.x * 64;
    for (int i = t; i < CIN * COUT; i += 256) sW[i] = W[i];
    for (int i = t; i < 64 * CIN; i += 256) {
        int r = i >> 7, k = i & (CIN - 1);
        int gr = row0 + r;
        sX[i] = (gr < M) ? x[(size_t)gr * CIN + k] : 0.0f;
    }
    __syncthreads();
    int col = t & 63;
    int rg  = t >> 6;
    float acc[16];
#pragma unroll
    for (int i = 0; i < 16; ++i) acc[i] = 0.0f;
    for (int k = 0; k < CIN; k += 4) {
        float w0 = sW[(k + 0) * COUT + col];
        float w1 = sW[(k + 1) * COUT + col];
        float w2 = sW[(k + 2) * COUT + col];
        float w3 = sW[(k + 3) * COUT + col];
#pragma unroll
        for (int i = 0; i < 16; ++i) {
            const float4 a = *reinterpret_cast<const float4*>(&sX[(rg * 16 + i) * CIN + k]);
            acc[i] = fmaf(a.x, w0, acc[i]);
            acc[i] = fmaf(a.y, w1, acc[i]);
            acc[i] = fmaf(a.z, w2, acc[i]);
            acc[i] = fmaf(a.w, w3, acc[i]);
        }
    }
#pragma unroll
    for (int i = 0; i < 16; ++i) {
        int gr = row0 + rg * 16 + i;
        if (gr < M) h[(size_t)gr * COUT + col] = acc[i];
    }
}

// fused gather: per fine node f (one wave, lane=channel):
//   out[f] = elu( sum_{e in CSR[f]} h[r_e]*coef_e + (inv[f]>=0 ? h[inv[f]]/deg_f : 0) + b )
__global__ __launch_bounds__(256) void k_gather(const float* __restrict__ h, const int* __restrict__ inv,
                                                const int* __restrict__ cnt, const int* __restrict__ offs,
                                                const int2* __restrict__ vals, const float* __restrict__ b,
                                                float* __restrict__ out, int N) {
    int wid  = (blockIdx.x * 256 + threadIdx.x) >> 6;
    int lane = threadIdx.x & 63;
    if (wid >= N) return;
    int c   = cnt[wid];
    int m   = c >> 16;
    int beg = offs[wid];
    float acc = 0.0f;
    for (int i = 0; i < m; ++i) {
        int2 v = vals[beg + i];                       // broadcast across wave
        acc = fmaf(h[(size_t)v.x * COUT + lane], __int_as_float(v.y), acc);
    }
    int rs = inv[wid];
    if (rs >= 0) {
        float degf = (float)((c & 0xFFFF) + 1);
        acc += h[(size_t)rs * COUT + lane] / degf;
    }
    acc += b[lane];
    out[(size_t)wid * COUT + lane] = acc > 0.0f ? acc : expm1f(acc);
}

extern "C" void kernel_launch(void* const* d_in, const int* in_sizes, int n_in,
                              void* d_out, int out_size, void* d_ws, size_t ws_size,
                              hipStream_t stream) {
    const float* x    = (const float*)d_in[0];
    const float* W    = (const float*)d_in[1];
    const float* b    = (const float*)d_in[2];
    const int*   edge = (const int*)d_in[3];
    const int*   mask = (const int*)d_in[4];
    const int Mx = in_sizes[0] / CIN;     // coarse rows (163968)
    const int E  = in_sizes[3] / 2;       // directed edges (3932160)
    const int N  = out_size / COUT;       // fine nodes (655360)

    const int* src = edge;
    const int* dst = edge + E;

    char* ws = (char*)d_ws;
    int*   cnt    = (int*)ws;                    ws += (size_t)N * 4;   // packed counts
    int*   inv    = (int*)ws;                    ws += (size_t)N * 4;
    int*   offs   = (int*)ws;                    ws += (size_t)N * 4;
    int*   cursor = (int*)ws;                    ws += (size_t)N * 4;
    int*   bsum   = (int*)ws;                    ws += 4096;            // scan block sums
    float* h      = (float*)ws;                  ws += (size_t)Mx * COUT * 4;
    int2*  vals   = (int2*)ws;                                          // up to E entries

    const int nb = (N + SCAN_CHUNK - 1) / SCAN_CHUNK;

    k_init <<<(N + 255) / 256, 256, 0, stream>>>(cnt, inv, N);
    k_mask <<<(Mx + 255) / 256, 256, 0, stream>>>(mask, inv, Mx);
    k_count<<<(E + 255) / 256, 256, 0, stream>>>(src, dst, inv, cnt, E);
    k_scan1<<<nb, 256, 0, stream>>>(cnt, bsum, N);
    k_scan2<<<1, 64, 0, stream>>>(bsum, nb);
    k_scan3<<<nb, 256, 0, stream>>>(cnt, bsum, offs, cursor, N);
    k_fill <<<(E + 255) / 256, 256, 0, stream>>>(src, dst, inv, cnt, cursor, vals, E);
    k_gemm <<<(Mx + 63) / 64, 256, 0, stream>>>(x, W, h, Mx);
    k_gather<<<((size_t)N + 3) / 4, 256, 0, stream>>>(h, inv, cnt, offs, vals, b, (float*)d_out, N);
}

// Round 3
// 496.203 us; speedup vs baseline: 1.7334x; 1.2428x over previous
//
#include <hip/hip_runtime.h>
#include <math.h>

#define CIN 128
#define COUT 64
#define SCAN_CHUNK 4096

// cnt[i] = 0, inv[i] = -1
__global__ __launch_bounds__(256) void k_init(int* __restrict__ cnt, int* __restrict__ inv, int N) {
    int i = blockIdx.x * 256 + threadIdx.x;
    if (i < N) { cnt[i] = 0; inv[i] = -1; }
}

// inv[unpool_mask[i]] = i
__global__ __launch_bounds__(256) void k_mask(const int* __restrict__ mask, int* __restrict__ inv, int M) {
    int i = blockIdx.x * 256 + threadIdx.x;
    if (i < M) inv[mask[i]] = i;
}

// packed histogram: low 16 = total in-degree, high 16 = coarse-src in-degree
__global__ __launch_bounds__(256) void k_count(const int4* __restrict__ src4, const int4* __restrict__ dst4,
                                               const int* __restrict__ inv, int* __restrict__ cnt, int E4) {
    int i = blockIdx.x * 256 + threadIdx.x;
    if (i >= E4) return;
    int4 s = src4[i], d = dst4[i];
    atomicAdd(&cnt[d.x], 1 + ((inv[s.x] >= 0) ? 65536 : 0));
    atomicAdd(&cnt[d.y], 1 + ((inv[s.y] >= 0) ? 65536 : 0));
    atomicAdd(&cnt[d.z], 1 + ((inv[s.z] >= 0) ? 65536 : 0));
    atomicAdd(&cnt[d.w], 1 + ((inv[s.w] >= 0) ? 65536 : 0));
}

// normc[i] = rsqrt(deg of the fine node owning coarse row i)
__global__ __launch_bounds__(256) void k_normc(const int* __restrict__ mask, const int* __restrict__ cnt,
                                               float* __restrict__ normc, int M) {
    int i = blockIdx.x * 256 + threadIdx.x;
    if (i < M) normc[i] = rsqrtf((float)((cnt[mask[i]] & 0xFFFF) + 1));
}

// ---- exclusive scan of m[f] = (cnt[f]>>16) + (inv[f]>=0) ----
__global__ __launch_bounds__(256) void k_scan1(const int* __restrict__ cnt, const int* __restrict__ inv,
                                               int* __restrict__ bsum, int N) {
    __shared__ int sm[256];
    int t = threadIdx.x;
    int base = blockIdx.x * SCAN_CHUNK + t * 16;
    int s = 0;
#pragma unroll
    for (int j = 0; j < 16; ++j) {
        int idx = base + j;
        if (idx < N) s += (cnt[idx] >> 16) + (inv[idx] >= 0 ? 1 : 0);
    }
    sm[t] = s; __syncthreads();
    for (int off = 128; off > 0; off >>= 1) { if (t < off) sm[t] += sm[t + off]; __syncthreads(); }
    if (t == 0) bsum[blockIdx.x] = sm[0];
}

__global__ __launch_bounds__(256) void k_scan2(int* __restrict__ bsum, int nb) {
    __shared__ int sm[256];
    int t = threadIdx.x;
    if (nb <= 256) {
        int v = (t < nb) ? bsum[t] : 0;
        sm[t] = v; __syncthreads();
        for (int off = 1; off < 256; off <<= 1) {
            int add = (t >= off) ? sm[t - off] : 0;
            __syncthreads();
            sm[t] += add;
            __syncthreads();
        }
        if (t < nb) bsum[t] = sm[t] - v;
    } else if (t == 0) {
        int run = 0;
        for (int i = 0; i < nb; ++i) { int v = bsum[i]; bsum[i] = run; run += v; }
    }
}

// meta[f] = (beg, m | deg<<16); cursor[f] = beg
__global__ __launch_bounds__(256) void k_scan3(const int* __restrict__ cnt, const int* __restrict__ inv,
                                               const int* __restrict__ bsum, int2* __restrict__ meta,
                                               int* __restrict__ cursor, int N) {
    __shared__ int sm[256];
    int t = threadIdx.x;
    int base = blockIdx.x * SCAN_CHUNK + t * 16;
    int mloc[16], dloc[16], loc[16];
    int s = 0;
#pragma unroll
    for (int j = 0; j < 16; ++j) {
        int idx = base + j;
        int c = (idx < N) ? cnt[idx] : 0;
        int sf = (idx < N) ? (inv[idx] >= 0 ? 1 : 0) : 0;
        int m = (c >> 16) + sf;
        mloc[j] = m; dloc[j] = (c & 0xFFFF) + 1;
        loc[j] = s; s += m;
    }
    sm[t] = s; __syncthreads();
    if (t == 0) {
        int run = bsum[blockIdx.x];
        for (int i = 0; i < 256; ++i) { int v = sm[i]; sm[i] = run; run += v; }
    }
    __syncthreads();
    int tb = sm[t];
#pragma unroll
    for (int j = 0; j < 16; ++j) {
        int idx = base + j;
        if (idx < N) {
            int o = tb + loc[j];
            meta[idx] = make_int2(o, mloc[j] | (dloc[j] << 16));
            cursor[idx] = o;
        }
    }
}

// self-loop CSR entries: vals[slot] = coarse row i (coef emerges as 1/deg in gather)
__global__ __launch_bounds__(256) void k_fill_self(const int* __restrict__ mask, int* __restrict__ cursor,
                                                   int* __restrict__ vals, int M) {
    int i = blockIdx.x * 256 + threadIdx.x;
    if (i >= M) return;
    int f = mask[i];
    int pos = atomicAdd(&cursor[f], 1);
    vals[pos] = i;
}

// edge CSR entries: for each edge with coarse src, vals[slot] = inv[src]
__global__ __launch_bounds__(256) void k_fill_edge(const int4* __restrict__ src4, const int4* __restrict__ dst4,
                                                   const int* __restrict__ inv, int* __restrict__ cursor,
                                                   int* __restrict__ vals, int E4) {
    int i = blockIdx.x * 256 + threadIdx.x;
    if (i >= E4) return;
    int4 s = src4[i], d = dst4[i];
    int r;
    r = inv[s.x]; if (r >= 0) { int p = atomicAdd(&cursor[d.x], 1); vals[p] = r; }
    r = inv[s.y]; if (r >= 0) { int p = atomicAdd(&cursor[d.y], 1); vals[p] = r; }
    r = inv[s.z]; if (r >= 0) { int p = atomicAdd(&cursor[d.z], 1); vals[p] = r; }
    r = inv[s.w]; if (r >= 0) { int p = atomicAdd(&cursor[d.w], 1); vals[p] = r; }
}

// h[M,64] = x[M,128] @ W[128,64]  (fp32, LDS-tiled, 64 rows/block)
__global__ __launch_bounds__(256) void k_gemm(const float* __restrict__ x, const float* __restrict__ W,
                                              float* __restrict__ h, int M) {
    __shared__ float sW[CIN * COUT];
    __shared__ float sX[64 * CIN];
    int t = threadIdx.x;
    int row0 = blockIdx.x * 64;
    for (int i = t; i < CIN * COUT; i += 256) sW[i] = W[i];
    for (int i = t; i < 64 * CIN; i += 256) {
        int r = i >> 7, k = i & (CIN - 1);
        int gr = row0 + r;
        sX[i] = (gr < M) ? x[(size_t)gr * CIN + k] : 0.0f;
    }
    __syncthreads();
    int col = t & 63;
    int rg  = t >> 6;
    float acc[16];
#pragma unroll
    for (int i = 0; i < 16; ++i) acc[i] = 0.0f;
    for (int k = 0; k < CIN; k += 4) {
        float w0 = sW[(k + 0) * COUT + col];
        float w1 = sW[(k + 1) * COUT + col];
        float w2 = sW[(k + 2) * COUT + col];
        float w3 = sW[(k + 3) * COUT + col];
#pragma unroll
        for (int i = 0; i < 16; ++i) {
            const float4 a = *reinterpret_cast<const float4*>(&sX[(rg * 16 + i) * CIN + k]);
            acc[i] = fmaf(a.x, w0, acc[i]);
            acc[i] = fmaf(a.y, w1, acc[i]);
            acc[i] = fmaf(a.z, w2, acc[i]);
            acc[i] = fmaf(a.w, w3, acc[i]);
        }
    }
#pragma unroll
    for (int i = 0; i < 16; ++i) {
        int gr = row0 + rg * 16 + i;
        if (gr < M) h[(size_t)gr * COUT + col] = acc[i];
    }
}

// fused gather: wave handles 4 consecutive fine nodes, lane = channel
// out[f] = elu( sum_j h[vals[beg_f+j]] * rsqrt(deg_f)*normc[vals[..]] + b )
__global__ __launch_bounds__(256) void k_gather(const float* __restrict__ h, const int2* __restrict__ meta,
                                                const int* __restrict__ vals, const float* __restrict__ normc,
                                                const float* __restrict__ b, float* __restrict__ out, int N4) {
    int wid  = (blockIdx.x * 256 + threadIdx.x) >> 6;
    int lane = threadIdx.x & 63;
    if (wid >= N4) return;
    int base = wid * 4;
    float bb = b[lane];
    int2 M0 = meta[base + 0], M1 = meta[base + 1], M2 = meta[base + 2], M3 = meta[base + 3];
    int bg[4] = { M0.x, M1.x, M2.x, M3.x };
    int mm[4] = { M0.y & 0xFFFF, M1.y & 0xFFFF, M2.y & 0xFFFF, M3.y & 0xFFFF };
    float nf[4] = { rsqrtf((float)(M0.y >> 16)), rsqrtf((float)(M1.y >> 16)),
                    rsqrtf((float)(M2.y >> 16)), rsqrtf((float)(M3.y >> 16)) };
    float acc[4] = { 0.f, 0.f, 0.f, 0.f };
    int mmax = max(max(mm[0], mm[1]), max(mm[2], mm[3]));
    for (int j = 0; j < mmax; ++j) {
        int v[4];
#pragma unroll
        for (int i = 0; i < 4; ++i) if (j < mm[i]) v[i] = vals[bg[i] + j];
#pragma unroll
        for (int i = 0; i < 4; ++i)
            if (j < mm[i])
                acc[i] = fmaf(h[(size_t)v[i] * COUT + lane], nf[i] * normc[v[i]], acc[i]);
    }
#pragma unroll
    for (int i = 0; i < 4; ++i) {
        float o = acc[i] + bb;
        out[((size_t)base + i) * COUT + lane] = o > 0.f ? o : expm1f(o);
    }
}

extern "C" void kernel_launch(void* const* d_in, const int* in_sizes, int n_in,
                              void* d_out, int out_size, void* d_ws, size_t ws_size,
                              hipStream_t stream) {
    const float* x    = (const float*)d_in[0];
    const float* W    = (const float*)d_in[1];
    const float* b    = (const float*)d_in[2];
    const int*   edge = (const int*)d_in[3];
    const int*   mask = (const int*)d_in[4];
    const int Mx = in_sizes[0] / CIN;     // coarse rows (163968)
    const int E  = in_sizes[3] / 2;       // directed edges (3932160)
    const int N  = out_size / COUT;       // fine nodes (655360)

    const int4* src4 = (const int4*)edge;
    const int4* dst4 = (const int4*)(edge + E);
    const int E4 = E / 4;

    char* ws = (char*)d_ws;
    int*   cnt    = (int*)ws;      ws += (size_t)N * 4;
    int*   inv    = (int*)ws;      ws += (size_t)N * 4;
    int*   cursor = (int*)ws;      ws += (size_t)N * 4;
    int2*  meta   = (int2*)ws;     ws += (size_t)N * 8;
    int*   bsum   = (int*)ws;      ws += 4096;
    float* normc  = (float*)ws;    ws += (size_t)Mx * 4;
    float* h      = (float*)ws;    ws += (size_t)Mx * COUT * 4;
    int*   vals   = (int*)ws;      // up to E + Mx entries

    const int nb = (N + SCAN_CHUNK - 1) / SCAN_CHUNK;

    k_init     <<<(N + 255) / 256, 256, 0, stream>>>(cnt, inv, N);
    k_mask     <<<(Mx + 255) / 256, 256, 0, stream>>>(mask, inv, Mx);
    k_count    <<<(E4 + 255) / 256, 256, 0, stream>>>(src4, dst4, inv, cnt, E4);
    k_normc    <<<(Mx + 255) / 256, 256, 0, stream>>>(mask, cnt, normc, Mx);
    k_scan1    <<<nb, 256, 0, stream>>>(cnt, inv, bsum, N);
    k_scan2    <<<1, 256, 0, stream>>>(bsum, nb);
    k_scan3    <<<nb, 256, 0, stream>>>(cnt, inv, bsum, meta, cursor, N);
    k_fill_self<<<(Mx + 255) / 256, 256, 0, stream>>>(mask, cursor, vals, Mx);
    k_fill_edge<<<(E4 + 255) / 256, 256, 0, stream>>>(src4, dst4, inv, cursor, vals, E4);
    k_gemm     <<<(Mx + 63) / 64, 256, 0, stream>>>(x, W, h, Mx);
    k_gather   <<<((N / 4) * 64 + 255) / 256, 256, 0, stream>>>(h, meta, vals, normc, b, (float*)d_out, N / 4);
}

// Round 4
// 434.164 us; speedup vs baseline: 1.9811x; 1.1429x over previous
//
#include <hip/hip_runtime.h>
#include <hip/hip_bf16.h>
#include <math.h>

#define CIN 128
#define COUT 64
#define SCAN_CHUNK 4096
#define BM 128
#define KC 64

// cnt[i] = 0, inv[i] = -1
__global__ __launch_bounds__(256) void k_init(int* __restrict__ cnt, int* __restrict__ inv, int N) {
    int i = blockIdx.x * 256 + threadIdx.x;
    if (i < N) { cnt[i] = 0; inv[i] = -1; }
}

// inv[unpool_mask[i]] = i
__global__ __launch_bounds__(256) void k_mask(const int* __restrict__ mask, int* __restrict__ inv, int M) {
    int i = blockIdx.x * 256 + threadIdx.x;
    if (i < M) inv[mask[i]] = i;
}

// packed histogram: low 16 = total in-degree, high 16 = coarse-src in-degree
__global__ __launch_bounds__(256) void k_count(const int4* __restrict__ src4, const int4* __restrict__ dst4,
                                               const int* __restrict__ inv, int* __restrict__ cnt, int E4) {
    int i = blockIdx.x * 256 + threadIdx.x;
    if (i >= E4) return;
    int4 s = src4[i], d = dst4[i];
    atomicAdd(&cnt[d.x], 1 + ((inv[s.x] >= 0) ? 65536 : 0));
    atomicAdd(&cnt[d.y], 1 + ((inv[s.y] >= 0) ? 65536 : 0));
    atomicAdd(&cnt[d.z], 1 + ((inv[s.z] >= 0) ? 65536 : 0));
    atomicAdd(&cnt[d.w], 1 + ((inv[s.w] >= 0) ? 65536 : 0));
}

// normc[i] = rsqrt(deg of the fine node owning coarse row i)
__global__ __launch_bounds__(256) void k_normc(const int* __restrict__ mask, const int* __restrict__ cnt,
                                               float* __restrict__ normc, int M) {
    int i = blockIdx.x * 256 + threadIdx.x;
    if (i < M) normc[i] = rsqrtf((float)((cnt[mask[i]] & 0xFFFF) + 1));
}

// ---- exclusive scan of m[f] = (cnt[f]>>16) + (inv[f]>=0) ----
__global__ __launch_bounds__(256) void k_scan1(const int* __restrict__ cnt, const int* __restrict__ inv,
                                               int* __restrict__ bsum, int N) {
    __shared__ int sm[256];
    int t = threadIdx.x;
    int base = blockIdx.x * SCAN_CHUNK + t * 16;
    int s = 0;
#pragma unroll
    for (int j = 0; j < 16; ++j) {
        int idx = base + j;
        if (idx < N) s += (cnt[idx] >> 16) + (inv[idx] >= 0 ? 1 : 0);
    }
    sm[t] = s; __syncthreads();
    for (int off = 128; off > 0; off >>= 1) { if (t < off) sm[t] += sm[t + off]; __syncthreads(); }
    if (t == 0) bsum[blockIdx.x] = sm[0];
}

__global__ __launch_bounds__(256) void k_scan2(int* __restrict__ bsum, int nb) {
    __shared__ int sm[256];
    int t = threadIdx.x;
    if (nb <= 256) {
        int v = (t < nb) ? bsum[t] : 0;
        sm[t] = v; __syncthreads();
        for (int off = 1; off < 256; off <<= 1) {
            int add = (t >= off) ? sm[t - off] : 0;
            __syncthreads();
            sm[t] += add;
            __syncthreads();
        }
        if (t < nb) bsum[t] = sm[t] - v;
    } else if (t == 0) {
        int run = 0;
        for (int i = 0; i < nb; ++i) { int v = bsum[i]; bsum[i] = run; run += v; }
    }
}

// meta[f] = (beg, m | deg<<16); cursor[f] = beg
__global__ __launch_bounds__(256) void k_scan3(const int* __restrict__ cnt, const int* __restrict__ inv,
                                               const int* __restrict__ bsum, int2* __restrict__ meta,
                                               int* __restrict__ cursor, int N) {
    __shared__ int sm[256];
    int t = threadIdx.x;
    int base = blockIdx.x * SCAN_CHUNK + t * 16;
    int mloc[16], dloc[16], loc[16];
    int s = 0;
#pragma unroll
    for (int j = 0; j < 16; ++j) {
        int idx = base + j;
        int c = (idx < N) ? cnt[idx] : 0;
        int sf = (idx < N) ? (inv[idx] >= 0 ? 1 : 0) : 0;
        int m = (c >> 16) + sf;
        mloc[j] = m; dloc[j] = (c & 0xFFFF) + 1;
        loc[j] = s; s += m;
    }
    sm[t] = s; __syncthreads();
    if (t == 0) {
        int run = bsum[blockIdx.x];
        for (int i = 0; i < 256; ++i) { int v = sm[i]; sm[i] = run; run += v; }
    }
    __syncthreads();
    int tb = sm[t];
#pragma unroll
    for (int j = 0; j < 16; ++j) {
        int idx = base + j;
        if (idx < N) {
            int o = tb + loc[j];
            meta[idx] = make_int2(o, mloc[j] | (dloc[j] << 16));
            cursor[idx] = o;
        }
    }
}

// self-loop CSR entries
__global__ __launch_bounds__(256) void k_fill_self(const int* __restrict__ mask, int* __restrict__ cursor,
                                                   int* __restrict__ vals, int M) {
    int i = blockIdx.x * 256 + threadIdx.x;
    if (i >= M) return;
    int f = mask[i];
    int pos = atomicAdd(&cursor[f], 1);
    vals[pos] = i;
}

// edge CSR entries: for each edge with coarse src, vals[slot] = inv[src]
__global__ __launch_bounds__(256) void k_fill_edge(const int4* __restrict__ src4, const int4* __restrict__ dst4,
                                                   const int* __restrict__ inv, int* __restrict__ cursor,
                                                   int* __restrict__ vals, int E4) {
    int i = blockIdx.x * 256 + threadIdx.x;
    if (i >= E4) return;
    int4 s = src4[i], d = dst4[i];
    int r;
    r = inv[s.x]; if (r >= 0) { int p = atomicAdd(&cursor[d.x], 1); vals[p] = r; }
    r = inv[s.y]; if (r >= 0) { int p = atomicAdd(&cursor[d.y], 1); vals[p] = r; }
    r = inv[s.z]; if (r >= 0) { int p = atomicAdd(&cursor[d.z], 1); vals[p] = r; }
    r = inv[s.w]; if (r >= 0) { int p = atomicAdd(&cursor[d.w], 1); vals[p] = r; }
}

// h[M,64](bf16) = x[M,128] @ W[128,64]
// 128-row x 64-col tile, KC=64 chunks; x staged transposed; 4x8 micro-tile/thread.
__global__ __launch_bounds__(256) void k_gemm(const float* __restrict__ x, const float* __restrict__ W,
                                              __hip_bfloat16* __restrict__ h, int M) {
    __shared__ float sXT[KC][BM];    // [k][row] 32 KB
    __shared__ float sW[KC][COUT];   // [k][col] 16 KB
    int t = threadIdx.x;
    int row0 = blockIdx.x * BM;
    int tr = (t & 31) * 4;   // 4 rows
    int tc = (t >> 5) * 8;   // 8 cols
    float acc[4][8];
#pragma unroll
    for (int i = 0; i < 4; ++i)
#pragma unroll
        for (int j = 0; j < 8; ++j) acc[i][j] = 0.f;

    for (int k0 = 0; k0 < CIN; k0 += KC) {
        __syncthreads();
        // stage x transposed: 128 rows x 64 k = 2048 float4
#pragma unroll
        for (int it = 0; it < 8; ++it) {
            int i = it * 256 + t;
            int row = i >> 4;
            int kq  = (i & 15) * 4;
            int gr = row0 + row;
            float4 v = (gr < M) ? *reinterpret_cast<const float4*>(&x[(size_t)gr * CIN + k0 + kq])
                                : make_float4(0.f, 0.f, 0.f, 0.f);
            sXT[kq + 0][row] = v.x;
            sXT[kq + 1][row] = v.y;
            sXT[kq + 2][row] = v.z;
            sXT[kq + 3][row] = v.w;
        }
        // stage W chunk: 64 k x 64 c = 1024 float4
#pragma unroll
        for (int it = 0; it < 4; ++it) {
            int i = it * 256 + t;
            int kk = i >> 4;
            int cq = (i & 15) * 4;
            *reinterpret_cast<float4*>(&sW[kk][cq]) =
                *reinterpret_cast<const float4*>(&W[(size_t)(k0 + kk) * COUT + cq]);
        }
        __syncthreads();
#pragma unroll 8
        for (int k = 0; k < KC; ++k) {
            float4 xa = *reinterpret_cast<const float4*>(&sXT[k][tr]);
            float4 wa = *reinterpret_cast<const float4*>(&sW[k][tc]);
            float4 wb = *reinterpret_cast<const float4*>(&sW[k][tc + 4]);
            float xs[4] = { xa.x, xa.y, xa.z, xa.w };
            float ws[8] = { wa.x, wa.y, wa.z, wa.w, wb.x, wb.y, wb.z, wb.w };
#pragma unroll
            for (int i = 0; i < 4; ++i)
#pragma unroll
                for (int j = 0; j < 8; ++j)
                    acc[i][j] = fmaf(xs[i], ws[j], acc[i][j]);
        }
    }
#pragma unroll
    for (int i = 0; i < 4; ++i) {
        int gr = row0 + tr + i;
        if (gr < M) {
            alignas(16) __hip_bfloat16 tmp[8];
#pragma unroll
            for (int j = 0; j < 8; ++j) tmp[j] = __float2bfloat16(acc[i][j]);
            *reinterpret_cast<float4*>(&h[(size_t)gr * COUT + tc]) = *reinterpret_cast<const float4*>(tmp);
        }
    }
}

// fused gather: wave handles 4 consecutive fine nodes, lane = channel
__global__ __launch_bounds__(256) void k_gather(const __hip_bfloat16* __restrict__ h, const int2* __restrict__ meta,
                                                const int* __restrict__ vals, const float* __restrict__ normc,
                                                const float* __restrict__ b, float* __restrict__ out, int N4) {
    int wid  = (blockIdx.x * 256 + threadIdx.x) >> 6;
    int lane = threadIdx.x & 63;
    if (wid >= N4) return;
    int base = wid * 4;
    float bb = b[lane];
    int2 M0 = meta[base + 0], M1 = meta[base + 1], M2 = meta[base + 2], M3 = meta[base + 3];
    int bg[4] = { M0.x, M1.x, M2.x, M3.x };
    int mm[4] = { M0.y & 0xFFFF, M1.y & 0xFFFF, M2.y & 0xFFFF, M3.y & 0xFFFF };
    float nf[4] = { rsqrtf((float)(M0.y >> 16)), rsqrtf((float)(M1.y >> 16)),
                    rsqrtf((float)(M2.y >> 16)), rsqrtf((float)(M3.y >> 16)) };
    float acc[4] = { 0.f, 0.f, 0.f, 0.f };
    int mmax = max(max(mm[0], mm[1]), max(mm[2], mm[3]));
    for (int j = 0; j < mmax; ++j) {
        int v[4];
#pragma unroll
        for (int i = 0; i < 4; ++i) if (j < mm[i]) v[i] = vals[bg[i] + j];
#pragma unroll
        for (int i = 0; i < 4; ++i)
            if (j < mm[i])
                acc[i] = fmaf(__bfloat162float(h[(size_t)v[i] * COUT + lane]),
                              nf[i] * normc[v[i]], acc[i]);
    }
#pragma unroll
    for (int i = 0; i < 4; ++i) {
        float o = acc[i] + bb;
        out[((size_t)base + i) * COUT + lane] = o > 0.f ? o : expm1f(o);
    }
}

extern "C" void kernel_launch(void* const* d_in, const int* in_sizes, int n_in,
                              void* d_out, int out_size, void* d_ws, size_t ws_size,
                              hipStream_t stream) {
    const float* x    = (const float*)d_in[0];
    const float* W    = (const float*)d_in[1];
    const float* b    = (const float*)d_in[2];
    const int*   edge = (const int*)d_in[3];
    const int*   mask = (const int*)d_in[4];
    const int Mx = in_sizes[0] / CIN;     // coarse rows (163968)
    const int E  = in_sizes[3] / 2;       // directed edges (3932160)
    const int N  = out_size / COUT;       // fine nodes (655360)

    const int4* src4 = (const int4*)edge;
    const int4* dst4 = (const int4*)(edge + E);
    const int E4 = E / 4;

    char* ws = (char*)d_ws;
    int*   cnt    = (int*)ws;      ws += (size_t)N * 4;
    int*   inv    = (int*)ws;      ws += (size_t)N * 4;
    int*   cursor = (int*)ws;      ws += (size_t)N * 4;
    int2*  meta   = (int2*)ws;     ws += (size_t)N * 8;
    int*   bsum   = (int*)ws;      ws += 4096;
    float* normc  = (float*)ws;    ws += (size_t)Mx * 4;
    __hip_bfloat16* h = (__hip_bfloat16*)ws;  ws += (size_t)Mx * COUT * 2;
    int*   vals   = (int*)ws;      // up to E + Mx entries

    const int nb = (N + SCAN_CHUNK - 1) / SCAN_CHUNK;

    k_init     <<<(N + 255) / 256, 256, 0, stream>>>(cnt, inv, N);
    k_mask     <<<(Mx + 255) / 256, 256, 0, stream>>>(mask, inv, Mx);
    k_count    <<<(E4 + 255) / 256, 256, 0, stream>>>(src4, dst4, inv, cnt, E4);
    k_normc    <<<(Mx + 255) / 256, 256, 0, stream>>>(mask, cnt, normc, Mx);
    k_scan1    <<<nb, 256, 0, stream>>>(cnt, inv, bsum, N);
    k_scan2    <<<1, 256, 0, stream>>>(bsum, nb);
    k_scan3    <<<nb, 256, 0, stream>>>(cnt, inv, bsum, meta, cursor, N);
    k_fill_self<<<(Mx + 255) / 256, 256, 0, stream>>>(mask, cursor, vals, Mx);
    k_fill_edge<<<(E4 + 255) / 256, 256, 0, stream>>>(src4, dst4, inv, cursor, vals, E4);
    k_gemm     <<<(Mx + BM - 1) / BM, 256, 0, stream>>>(x, W, h, Mx);
    k_gather   <<<((N / 4) * 64 + 255) / 256, 256, 0, stream>>>(h, meta, vals, normc, b, (float*)d_out, N / 4);
}

// Round 5
// 433.114 us; speedup vs baseline: 1.9859x; 1.0024x over previous
//
#include <hip/hip_runtime.h>
#include <hip/hip_bf16.h>
#include <math.h>

#define CIN 128
#define COUT 64
#define SCAN_CHUNK 4096
#define BM 128
#define KC 64
#define BSAMP 64      // samples in batch (fixed by problem)
#define NFINE 10242   // fine nodes per sample (fixed by problem)

// cnt[i] = 0, inv[i] = -1
__global__ __launch_bounds__(256) void k_init(int* __restrict__ cnt, int* __restrict__ inv, int N) {
    int i = blockIdx.x * 256 + threadIdx.x;
    if (i < N) { cnt[i] = 0; inv[i] = -1; }
}

// inv[unpool_mask[i]] = i
__global__ __launch_bounds__(256) void k_mask(const int* __restrict__ mask, int* __restrict__ inv, int M) {
    int i = blockIdx.x * 256 + threadIdx.x;
    if (i < M) inv[mask[i]] = i;
}

// per-sample LDS histogram: low 16 = total in-degree, high 16 = coarse-src in-degree.
// One block per sample; out-of-window dst falls back to global atomic (correct for any input).
__global__ __launch_bounds__(256) void k_count(const int* __restrict__ src, const int* __restrict__ dst,
                                               const int* __restrict__ inv, int* __restrict__ cnt, int EPS) {
    __shared__ int lh[NFINE];
    int t = threadIdx.x, b = blockIdx.x;
    for (int j = t; j < NFINE; j += 256) lh[j] = 0;
    __syncthreads();
    int base = b * NFINE;
    const int4* s4 = (const int4*)(src + (size_t)b * EPS);
    const int4* d4 = (const int4*)(dst + (size_t)b * EPS);
    int n4 = EPS / 4;
    for (int i = t; i < n4; i += 256) {
        int4 s = s4[i], d = d4[i];
        int a0 = 1 + ((inv[s.x] >= 0) ? 65536 : 0);
        int a1 = 1 + ((inv[s.y] >= 0) ? 65536 : 0);
        int a2 = 1 + ((inv[s.z] >= 0) ? 65536 : 0);
        int a3 = 1 + ((inv[s.w] >= 0) ? 65536 : 0);
        int l0 = d.x - base, l1 = d.y - base, l2 = d.z - base, l3 = d.w - base;
        if ((unsigned)l0 < NFINE) atomicAdd(&lh[l0], a0); else atomicAdd(&cnt[d.x], a0);
        if ((unsigned)l1 < NFINE) atomicAdd(&lh[l1], a1); else atomicAdd(&cnt[d.y], a1);
        if ((unsigned)l2 < NFINE) atomicAdd(&lh[l2], a2); else atomicAdd(&cnt[d.z], a2);
        if ((unsigned)l3 < NFINE) atomicAdd(&lh[l3], a3); else atomicAdd(&cnt[d.w], a3);
    }
    __syncthreads();
    for (int j = t; j < NFINE; j += 256) {
        int v = lh[j];
        if (v) atomicAdd(&cnt[base + j], v);
    }
}

// normc[i] = rsqrt(deg of the fine node owning coarse row i)
__global__ __launch_bounds__(256) void k_normc(const int* __restrict__ mask, const int* __restrict__ cnt,
                                               float* __restrict__ normc, int M) {
    int i = blockIdx.x * 256 + threadIdx.x;
    if (i < M) normc[i] = rsqrtf((float)((cnt[mask[i]] & 0xFFFF) + 1));
}

// ---- exclusive scan of m[f] = (cnt[f]>>16) + (inv[f]>=0) ----
__global__ __launch_bounds__(256) void k_scan1(const int* __restrict__ cnt, const int* __restrict__ inv,
                                               int* __restrict__ bsum, int N) {
    __shared__ int sm[256];
    int t = threadIdx.x;
    int base = blockIdx.x * SCAN_CHUNK + t * 16;
    int s = 0;
#pragma unroll
    for (int j = 0; j < 16; ++j) {
        int idx = base + j;
        if (idx < N) s += (cnt[idx] >> 16) + (inv[idx] >= 0 ? 1 : 0);
    }
    sm[t] = s; __syncthreads();
    for (int off = 128; off > 0; off >>= 1) { if (t < off) sm[t] += sm[t + off]; __syncthreads(); }
    if (t == 0) bsum[blockIdx.x] = sm[0];
}

__global__ __launch_bounds__(256) void k_scan2(int* __restrict__ bsum, int nb) {
    __shared__ int sm[256];
    int t = threadIdx.x;
    if (nb <= 256) {
        int v = (t < nb) ? bsum[t] : 0;
        sm[t] = v; __syncthreads();
        for (int off = 1; off < 256; off <<= 1) {
            int add = (t >= off) ? sm[t - off] : 0;
            __syncthreads();
            sm[t] += add;
            __syncthreads();
        }
        if (t < nb) bsum[t] = sm[t] - v;
    } else if (t == 0) {
        int run = 0;
        for (int i = 0; i < nb; ++i) { int v = bsum[i]; bsum[i] = run; run += v; }
    }
}

// meta[f] = (beg, m | deg<<16); cursor[f] = beg
__global__ __launch_bounds__(256) void k_scan3(const int* __restrict__ cnt, const int* __restrict__ inv,
                                               const int* __restrict__ bsum, int2* __restrict__ meta,
                                               int* __restrict__ cursor, int N) {
    __shared__ int sm[256];
    int t = threadIdx.x;
    int base = blockIdx.x * SCAN_CHUNK + t * 16;
    int mloc[16], dloc[16], loc[16];
    int s = 0;
#pragma unroll
    for (int j = 0; j < 16; ++j) {
        int idx = base + j;
        int c = (idx < N) ? cnt[idx] : 0;
        int sf = (idx < N) ? (inv[idx] >= 0 ? 1 : 0) : 0;
        int m = (c >> 16) + sf;
        mloc[j] = m; dloc[j] = (c & 0xFFFF) + 1;
        loc[j] = s; s += m;
    }
    sm[t] = s; __syncthreads();
    if (t == 0) {
        int run = bsum[blockIdx.x];
        for (int i = 0; i < 256; ++i) { int v = sm[i]; sm[i] = run; run += v; }
    }
    __syncthreads();
    int tb = sm[t];
#pragma unroll
    for (int j = 0; j < 16; ++j) {
        int idx = base + j;
        if (idx < N) {
            int o = tb + loc[j];
            meta[idx] = make_int2(o, mloc[j] | (dloc[j] << 16));
            cursor[idx] = o;
        }
    }
}

// self-loop CSR entries
__global__ __launch_bounds__(256) void k_fill_self(const int* __restrict__ mask, int* __restrict__ cursor,
                                                   int* __restrict__ vals, int M) {
    int i = blockIdx.x * 256 + threadIdx.x;
    if (i >= M) return;
    int f = mask[i];
    int pos = atomicAdd(&cursor[f], 1);
    vals[pos] = i;
}

// per-sample CSR fill: local count pass -> bulk slot alloc (atomic, so foreign edges stay
// collision-free) -> slot assignment via LDS cursors. One block per sample.
__global__ __launch_bounds__(256) void k_fill_edge(const int* __restrict__ src, const int* __restrict__ dst,
                                                   const int* __restrict__ inv, int* __restrict__ cursor,
                                                   int* __restrict__ vals, int EPS) {
    __shared__ int lh[NFINE];
    int t = threadIdx.x, b = blockIdx.x;
    for (int j = t; j < NFINE; j += 256) lh[j] = 0;
    __syncthreads();
    int base = b * NFINE;
    const int4* s4 = (const int4*)(src + (size_t)b * EPS);
    const int4* d4 = (const int4*)(dst + (size_t)b * EPS);
    int n4 = EPS / 4;
    // pass A: local contributing-edge counts
    for (int i = t; i < n4; i += 256) {
        int4 s = s4[i], d = d4[i];
        int l;
        if (inv[s.x] >= 0) { l = d.x - base; if ((unsigned)l < NFINE) atomicAdd(&lh[l], 1); }
        if (inv[s.y] >= 0) { l = d.y - base; if ((unsigned)l < NFINE) atomicAdd(&lh[l], 1); }
        if (inv[s.z] >= 0) { l = d.z - base; if ((unsigned)l < NFINE) atomicAdd(&lh[l], 1); }
        if (inv[s.w] >= 0) { l = d.w - base; if ((unsigned)l < NFINE) atomicAdd(&lh[l], 1); }
    }
    __syncthreads();
    // bulk alloc: lh[j] becomes the running global slot cursor for node base+j
    for (int j = t; j < NFINE; j += 256) {
        int v = lh[j];
        if (v) lh[j] = atomicAdd(&cursor[base + j], v);
    }
    __syncthreads();
    // pass B: assign slots
    for (int i = t; i < n4; i += 256) {
        int4 s = s4[i], d = d4[i];
        int r, l, pos;
        r = inv[s.x]; if (r >= 0) { l = d.x - base; pos = ((unsigned)l < NFINE) ? atomicAdd(&lh[l], 1) : atomicAdd(&cursor[d.x], 1); vals[pos] = r; }
        r = inv[s.y]; if (r >= 0) { l = d.y - base; pos = ((unsigned)l < NFINE) ? atomicAdd(&lh[l], 1) : atomicAdd(&cursor[d.y], 1); vals[pos] = r; }
        r = inv[s.z]; if (r >= 0) { l = d.z - base; pos = ((unsigned)l < NFINE) ? atomicAdd(&lh[l], 1) : atomicAdd(&cursor[d.z], 1); vals[pos] = r; }
        r = inv[s.w]; if (r >= 0) { l = d.w - base; pos = ((unsigned)l < NFINE) ? atomicAdd(&lh[l], 1) : atomicAdd(&cursor[d.w], 1); vals[pos] = r; }
    }
}

// h[M,64](bf16) = x[M,128] @ W[128,64]
__global__ __launch_bounds__(256) void k_gemm(const float* __restrict__ x, const float* __restrict__ W,
                                              __hip_bfloat16* __restrict__ h, int M) {
    __shared__ float sXT[KC][BM];
    __shared__ float sW[KC][COUT];
    int t = threadIdx.x;
    int row0 = blockIdx.x * BM;
    int tr = (t & 31) * 4;
    int tc = (t >> 5) * 8;
    float acc[4][8];
#pragma unroll
    for (int i = 0; i < 4; ++i)
#pragma unroll
        for (int j = 0; j < 8; ++j) acc[i][j] = 0.f;

    for (int k0 = 0; k0 < CIN; k0 += KC) {
        __syncthreads();
#pragma unroll
        for (int it = 0; it < 8; ++it) {
            int i = it * 256 + t;
            int row = i >> 4;
            int kq  = (i & 15) * 4;
            int gr = row0 + row;
            float4 v = (gr < M) ? *reinterpret_cast<const float4*>(&x[(size_t)gr * CIN + k0 + kq])
                                : make_float4(0.f, 0.f, 0.f, 0.f);
            sXT[kq + 0][row] = v.x;
            sXT[kq + 1][row] = v.y;
            sXT[kq + 2][row] = v.z;
            sXT[kq + 3][row] = v.w;
        }
#pragma unroll
        for (int it = 0; it < 4; ++it) {
            int i = it * 256 + t;
            int kk = i >> 4;
            int cq = (i & 15) * 4;
            *reinterpret_cast<float4*>(&sW[kk][cq]) =
                *reinterpret_cast<const float4*>(&W[(size_t)(k0 + kk) * COUT + cq]);
        }
        __syncthreads();
#pragma unroll 8
        for (int k = 0; k < KC; ++k) {
            float4 xa = *reinterpret_cast<const float4*>(&sXT[k][tr]);
            float4 wa = *reinterpret_cast<const float4*>(&sW[k][tc]);
            float4 wb = *reinterpret_cast<const float4*>(&sW[k][tc + 4]);
            float xs[4] = { xa.x, xa.y, xa.z, xa.w };
            float ws[8] = { wa.x, wa.y, wa.z, wa.w, wb.x, wb.y, wb.z, wb.w };
#pragma unroll
            for (int i = 0; i < 4; ++i)
#pragma unroll
                for (int j = 0; j < 8; ++j)
                    acc[i][j] = fmaf(xs[i], ws[j], acc[i][j]);
        }
    }
#pragma unroll
    for (int i = 0; i < 4; ++i) {
        int gr = row0 + tr + i;
        if (gr < M) {
            alignas(16) __hip_bfloat16 tmp[8];
#pragma unroll
            for (int j = 0; j < 8; ++j) tmp[j] = __float2bfloat16(acc[i][j]);
            *reinterpret_cast<float4*>(&h[(size_t)gr * COUT + tc]) = *reinterpret_cast<const float4*>(tmp);
        }
    }
}

// fused gather: wave handles 8 consecutive fine nodes, lane = channel
__global__ __launch_bounds__(256) void k_gather(const __hip_bfloat16* __restrict__ h, const int2* __restrict__ meta,
                                                const int* __restrict__ vals, const float* __restrict__ normc,
                                                const float* __restrict__ b, float* __restrict__ out, int N8) {
    int wid  = (blockIdx.x * 256 + threadIdx.x) >> 6;
    int lane = threadIdx.x & 63;
    if (wid >= N8) return;
    int base = wid * 8;
    float bb = b[lane];
    int bg[8], mm[8];
    float nf[8], acc[8];
    int mmax = 0;
#pragma unroll
    for (int i = 0; i < 8; ++i) {
        int2 Mi = meta[base + i];
        bg[i] = Mi.x;
        mm[i] = Mi.y & 0xFFFF;
        nf[i] = rsqrtf((float)(Mi.y >> 16));
        acc[i] = 0.f;
        mmax = max(mmax, mm[i]);
    }
    for (int j = 0; j < mmax; ++j) {
        int v[8];
#pragma unroll
        for (int i = 0; i < 8; ++i) if (j < mm[i]) v[i] = vals[bg[i] + j];
#pragma unroll
        for (int i = 0; i < 8; ++i)
            if (j < mm[i])
                acc[i] = fmaf(__bfloat162float(h[(size_t)v[i] * COUT + lane]),
                              nf[i] * normc[v[i]], acc[i]);
    }
#pragma unroll
    for (int i = 0; i < 8; ++i) {
        float o = acc[i] + bb;
        out[((size_t)base + i) * COUT + lane] = o > 0.f ? o : expm1f(o);
    }
}

extern "C" void kernel_launch(void* const* d_in, const int* in_sizes, int n_in,
                              void* d_out, int out_size, void* d_ws, size_t ws_size,
                              hipStream_t stream) {
    const float* x    = (const float*)d_in[0];
    const float* W    = (const float*)d_in[1];
    const float* b    = (const float*)d_in[2];
    const int*   edge = (const int*)d_in[3];
    const int*   mask = (const int*)d_in[4];
    const int Mx = in_sizes[0] / CIN;     // coarse rows (163968)
    const int E  = in_sizes[3] / 2;       // directed edges (3932160)
    const int N  = out_size / COUT;       // fine nodes (655360)
    const int EPS = E / BSAMP;            // edges per sample (61440)

    const int* src = edge;
    const int* dst = edge + E;

    char* ws = (char*)d_ws;
    int*   cnt    = (int*)ws;      ws += (size_t)N * 4;
    int*   inv    = (int*)ws;      ws += (size_t)N * 4;
    int*   cursor = (int*)ws;      ws += (size_t)N * 4;
    int2*  meta   = (int2*)ws;     ws += (size_t)N * 8;
    int*   bsum   = (int*)ws;      ws += 4096;
    float* normc  = (float*)ws;    ws += (size_t)Mx * 4;
    __hip_bfloat16* h = (__hip_bfloat16*)ws;  ws += (size_t)Mx * COUT * 2;
    int*   vals   = (int*)ws;      // up to E + Mx entries

    const int nb = (N + SCAN_CHUNK - 1) / SCAN_CHUNK;

    k_init     <<<(N + 255) / 256, 256, 0, stream>>>(cnt, inv, N);
    k_mask     <<<(Mx + 255) / 256, 256, 0, stream>>>(mask, inv, Mx);
    k_count    <<<BSAMP, 256, 0, stream>>>(src, dst, inv, cnt, EPS);
    k_normc    <<<(Mx + 255) / 256, 256, 0, stream>>>(mask, cnt, normc, Mx);
    k_scan1    <<<nb, 256, 0, stream>>>(cnt, inv, bsum, N);
    k_scan2    <<<1, 256, 0, stream>>>(bsum, nb);
    k_scan3    <<<nb, 256, 0, stream>>>(cnt, inv, bsum, meta, cursor, N);
    k_fill_self<<<(Mx + 255) / 256, 256, 0, stream>>>(mask, cursor, vals, Mx);
    k_fill_edge<<<BSAMP, 256, 0, stream>>>(src, dst, inv, cursor, vals, EPS);
    k_gemm     <<<(Mx + BM - 1) / BM, 256, 0, stream>>>(x, W, h, Mx);
    k_gather   <<<((N / 8) * 64 + 255) / 256, 256, 0, stream>>>(h, meta, vals, normc, b, (float*)d_out, N / 8);
}

// Round 6
// 362.074 us; speedup vs baseline: 2.3755x; 1.1962x over previous
//
#include <hip/hip_runtime.h>
#include <hip/hip_bf16.h>
#include <math.h>

#define CIN 128
#define COUT 64
#define BM 128
#define KC 64
#define BSAMP 64      // samples in batch (fixed by problem)
#define NFINE 10242   // fine nodes per sample (fixed by problem)
#define NRNG 8        // node-ranges per sample
#define RS 1281       // ceil(NFINE / NRNG)
#define HT 512        // threads for hist/fill kernels

// inv[i] = -1 ; gctr = 0
__global__ __launch_bounds__(256) void k_init(int* __restrict__ inv, int* __restrict__ gctr, int N) {
    int i = blockIdx.x * 256 + threadIdx.x;
    if (i < N) inv[i] = -1;
    if (i == 0) *gctr = 0;
}

// inv[unpool_mask[i]] = i
__global__ __launch_bounds__(256) void k_mask(const int* __restrict__ mask, int* __restrict__ inv, int M) {
    int i = blockIdx.x * 256 + threadIdx.x;
    if (i < M) inv[mask[i]] = i;
}

// One block per (sample, node-range): LDS histogram (deg | m<<16) over the range,
// fused block scan + one global atomic to allocate CSR space, write meta directly.
__global__ __launch_bounds__(HT) void k_hist(const int* __restrict__ src, const int* __restrict__ dst,
                                             const int* __restrict__ inv, int2* __restrict__ meta,
                                             int* __restrict__ gctr, int EPS) {
    __shared__ int lh[RS];
    __shared__ int sm[HT];
    __shared__ int gbase;
    int t = threadIdx.x;
    int b = blockIdx.x / NRNG, r = blockIdx.x % NRNG;
    int sampbase = b * NFINE;
    int lo = r * RS;
    int nlocal = min(RS, NFINE - lo);
    for (int j = t; j < nlocal; j += HT) lh[j] = 0;
    __syncthreads();
    const int4* s4 = (const int4*)(src + (size_t)b * EPS);
    const int4* d4 = (const int4*)(dst + (size_t)b * EPS);
    int n4 = EPS / 4;
    for (int i = t; i < n4; i += HT) {
        int4 s = s4[i], d = d4[i];
        int l;
        l = d.x - sampbase - lo; if ((unsigned)l < (unsigned)nlocal) atomicAdd(&lh[l], 1 + ((inv[s.x] >= 0) ? 65536 : 0));
        l = d.y - sampbase - lo; if ((unsigned)l < (unsigned)nlocal) atomicAdd(&lh[l], 1 + ((inv[s.y] >= 0) ? 65536 : 0));
        l = d.z - sampbase - lo; if ((unsigned)l < (unsigned)nlocal) atomicAdd(&lh[l], 1 + ((inv[s.z] >= 0) ? 65536 : 0));
        l = d.w - sampbase - lo; if ((unsigned)l < (unsigned)nlocal) atomicAdd(&lh[l], 1 + ((inv[s.w] >= 0) ? 65536 : 0));
    }
    __syncthreads();
    // per-thread partial counts over strided entries (3 per thread)
    int mj[3];
    int psum = 0;
#pragma unroll
    for (int k = 0; k < 3; ++k) {
        int idx = t + k * HT;
        int m = 0;
        if (idx < nlocal) {
            int gf = sampbase + lo + idx;
            m = (lh[idx] >> 16) + (inv[gf] >= 0 ? 1 : 0);   // + self-loop entry
        }
        mj[k] = m; psum += m;
    }
    sm[t] = psum; __syncthreads();
    for (int off = 1; off < HT; off <<= 1) {                 // inclusive scan
        int add = (t >= off) ? sm[t - off] : 0;
        __syncthreads();
        sm[t] += add;
        __syncthreads();
    }
    if (t == HT - 1) gbase = atomicAdd(gctr, sm[HT - 1]);
    __syncthreads();
    int run = gbase + sm[t] - psum;                          // exclusive base for this thread
#pragma unroll
    for (int k = 0; k < 3; ++k) {
        int idx = t + k * HT;
        if (idx < nlocal) {
            int gf = sampbase + lo + idx;
            int deg = (lh[idx] & 0xFFFF) + 1;
            meta[gf] = make_int2(run, mj[k] | (deg << 16));
            run += mj[k];
        }
    }
}

// normc[i] = rsqrt(deg of the fine node owning coarse row i)
__global__ __launch_bounds__(256) void k_normc(const int* __restrict__ mask, const int2* __restrict__ meta,
                                               float* __restrict__ normc, int M) {
    int i = blockIdx.x * 256 + threadIdx.x;
    if (i < M) normc[i] = rsqrtf((float)(meta[mask[i]].y >> 16));
}

// One block per (sample, node-range): write self-loop entries, then assign edge slots
// via LDS cursors; plain scattered stores, no global atomics.
__global__ __launch_bounds__(HT) void k_fill(const int* __restrict__ src, const int* __restrict__ dst,
                                             const int* __restrict__ inv, const int2* __restrict__ meta,
                                             int* __restrict__ vals, int EPS) {
    __shared__ int lc[RS];
    int t = threadIdx.x;
    int b = blockIdx.x / NRNG, r = blockIdx.x % NRNG;
    int sampbase = b * NFINE;
    int lo = r * RS;
    int nlocal = min(RS, NFINE - lo);
    for (int idx = t; idx < nlocal; idx += HT) {
        int gf = sampbase + lo + idx;
        int beg = meta[gf].x;
        int rv = inv[gf];
        if (rv >= 0) { vals[beg] = rv; ++beg; }              // self-loop entry first
        lc[idx] = beg;
    }
    __syncthreads();
    const int4* s4 = (const int4*)(src + (size_t)b * EPS);
    const int4* d4 = (const int4*)(dst + (size_t)b * EPS);
    int n4 = EPS / 4;
    for (int i = t; i < n4; i += HT) {
        int4 s = s4[i], d = d4[i];
        int l, rr;
        l = d.x - sampbase - lo; if ((unsigned)l < (unsigned)nlocal) { rr = inv[s.x]; if (rr >= 0) { int p = atomicAdd(&lc[l], 1); vals[p] = rr; } }
        l = d.y - sampbase - lo; if ((unsigned)l < (unsigned)nlocal) { rr = inv[s.y]; if (rr >= 0) { int p = atomicAdd(&lc[l], 1); vals[p] = rr; } }
        l = d.z - sampbase - lo; if ((unsigned)l < (unsigned)nlocal) { rr = inv[s.z]; if (rr >= 0) { int p = atomicAdd(&lc[l], 1); vals[p] = rr; } }
        l = d.w - sampbase - lo; if ((unsigned)l < (unsigned)nlocal) { rr = inv[s.w]; if (rr >= 0) { int p = atomicAdd(&lc[l], 1); vals[p] = rr; } }
    }
}

// h[M,64](bf16) = x[M,128] @ W[128,64]
__global__ __launch_bounds__(256) void k_gemm(const float* __restrict__ x, const float* __restrict__ W,
                                              __hip_bfloat16* __restrict__ h, int M) {
    __shared__ float sXT[KC][BM];
    __shared__ float sW[KC][COUT];
    int t = threadIdx.x;
    int row0 = blockIdx.x * BM;
    int tr = (t & 31) * 4;
    int tc = (t >> 5) * 8;
    float acc[4][8];
#pragma unroll
    for (int i = 0; i < 4; ++i)
#pragma unroll
        for (int j = 0; j < 8; ++j) acc[i][j] = 0.f;

    for (int k0 = 0; k0 < CIN; k0 += KC) {
        __syncthreads();
#pragma unroll
        for (int it = 0; it < 8; ++it) {
            int i = it * 256 + t;
            int row = i >> 4;
            int kq  = (i & 15) * 4;
            int gr = row0 + row;
            float4 v = (gr < M) ? *reinterpret_cast<const float4*>(&x[(size_t)gr * CIN + k0 + kq])
                                : make_float4(0.f, 0.f, 0.f, 0.f);
            sXT[kq + 0][row] = v.x;
            sXT[kq + 1][row] = v.y;
            sXT[kq + 2][row] = v.z;
            sXT[kq + 3][row] = v.w;
        }
#pragma unroll
        for (int it = 0; it < 4; ++it) {
            int i = it * 256 + t;
            int kk = i >> 4;
            int cq = (i & 15) * 4;
            *reinterpret_cast<float4*>(&sW[kk][cq]) =
                *reinterpret_cast<const float4*>(&W[(size_t)(k0 + kk) * COUT + cq]);
        }
        __syncthreads();
#pragma unroll 8
        for (int k = 0; k < KC; ++k) {
            float4 xa = *reinterpret_cast<const float4*>(&sXT[k][tr]);
            float4 wa = *reinterpret_cast<const float4*>(&sW[k][tc]);
            float4 wb = *reinterpret_cast<const float4*>(&sW[k][tc + 4]);
            float xs[4] = { xa.x, xa.y, xa.z, xa.w };
            float ws[8] = { wa.x, wa.y, wa.z, wa.w, wb.x, wb.y, wb.z, wb.w };
#pragma unroll
            for (int i = 0; i < 4; ++i)
#pragma unroll
                for (int j = 0; j < 8; ++j)
                    acc[i][j] = fmaf(xs[i], ws[j], acc[i][j]);
        }
    }
#pragma unroll
    for (int i = 0; i < 4; ++i) {
        int gr = row0 + tr + i;
        if (gr < M) {
            alignas(16) __hip_bfloat16 tmp[8];
#pragma unroll
            for (int j = 0; j < 8; ++j) tmp[j] = __float2bfloat16(acc[i][j]);
            *reinterpret_cast<float4*>(&h[(size_t)gr * COUT + tc]) = *reinterpret_cast<const float4*>(tmp);
        }
    }
}

// fused gather: wave handles 8 consecutive fine nodes, lane = channel
__global__ __launch_bounds__(256) void k_gather(const __hip_bfloat16* __restrict__ h, const int2* __restrict__ meta,
                                                const int* __restrict__ vals, const float* __restrict__ normc,
                                                const float* __restrict__ b, float* __restrict__ out, int N8) {
    int wid  = (blockIdx.x * 256 + threadIdx.x) >> 6;
    int lane = threadIdx.x & 63;
    if (wid >= N8) return;
    int base = wid * 8;
    float bb = b[lane];
    int bg[8], mm[8];
    float nf[8], acc[8];
    int mmax = 0;
#pragma unroll
    for (int i = 0; i < 8; ++i) {
        int2 Mi = meta[base + i];
        bg[i] = Mi.x;
        mm[i] = Mi.y & 0xFFFF;
        nf[i] = rsqrtf((float)(Mi.y >> 16));
        acc[i] = 0.f;
        mmax = max(mmax, mm[i]);
    }
    for (int j = 0; j < mmax; ++j) {
        int v[8];
#pragma unroll
        for (int i = 0; i < 8; ++i) if (j < mm[i]) v[i] = vals[bg[i] + j];
#pragma unroll
        for (int i = 0; i < 8; ++i)
            if (j < mm[i])
                acc[i] = fmaf(__bfloat162float(h[(size_t)v[i] * COUT + lane]),
                              nf[i] * normc[v[i]], acc[i]);
    }
#pragma unroll
    for (int i = 0; i < 8; ++i) {
        float o = acc[i] + bb;
        out[((size_t)base + i) * COUT + lane] = o > 0.f ? o : expm1f(o);
    }
}

extern "C" void kernel_launch(void* const* d_in, const int* in_sizes, int n_in,
                              void* d_out, int out_size, void* d_ws, size_t ws_size,
                              hipStream_t stream) {
    const float* x    = (const float*)d_in[0];
    const float* W    = (const float*)d_in[1];
    const float* b    = (const float*)d_in[2];
    const int*   edge = (const int*)d_in[3];
    const int*   mask = (const int*)d_in[4];
    const int Mx = in_sizes[0] / CIN;     // coarse rows (163968)
    const int E  = in_sizes[3] / 2;       // directed edges (3932160)
    const int N  = out_size / COUT;       // fine nodes (655360)
    const int EPS = E / BSAMP;            // edges per sample (61440)

    const int* src = edge;
    const int* dst = edge + E;

    char* ws = (char*)d_ws;
    int*   inv    = (int*)ws;      ws += (size_t)N * 4;
    int2*  meta   = (int2*)ws;     ws += (size_t)N * 8;
    int*   gctr   = (int*)ws;      ws += 256;
    float* normc  = (float*)ws;    ws += (size_t)Mx * 4;
    __hip_bfloat16* h = (__hip_bfloat16*)ws;  ws += (size_t)Mx * COUT * 2;
    int*   vals   = (int*)ws;      // up to E + Mx entries

    k_init  <<<(N + 255) / 256, 256, 0, stream>>>(inv, gctr, N);
    k_mask  <<<(Mx + 255) / 256, 256, 0, stream>>>(mask, inv, Mx);
    k_hist  <<<BSAMP * NRNG, HT, 0, stream>>>(src, dst, inv, meta, gctr, EPS);
    k_normc <<<(Mx + 255) / 256, 256, 0, stream>>>(mask, meta, normc, Mx);
    k_fill  <<<BSAMP * NRNG, HT, 0, stream>>>(src, dst, inv, meta, vals, EPS);
    k_gemm  <<<(Mx + BM - 1) / BM, 256, 0, stream>>>(x, W, h, Mx);
    k_gather<<<((N / 8) * 64 + 255) / 256, 256, 0, stream>>>(h, meta, vals, normc, b, (float*)d_out, N / 8);
}

// Round 7
// 261.590 us; speedup vs baseline: 3.2880x; 1.3841x over previous
//
#include <hip/hip_runtime.h>
#include <hip/hip_bf16.h>
#include <math.h>

#define CIN 128
#define COUT 64
#define BM 128
#define KC 64
#define BSAMP 64      // samples in batch (fixed by problem)
#define NFINE 10242   // fine nodes per sample (fixed by problem)
#define NRNG 8        // node-ranges per sample
#define RS 1281       // ceil(NFINE / NRNG)
#define HT 512        // threads for build kernel
#define CAP 12288     // LDS edge-cache capacity (mean load 1920; overflow -> rescan)

// inv[i] = -1 ; gctr = 0
__global__ __launch_bounds__(256) void k_init(int* __restrict__ inv, int* __restrict__ gctr, int N) {
    int i = blockIdx.x * 256 + threadIdx.x;
    if (i < N) inv[i] = -1;
    if (i == 0) *gctr = 0;
}

// inv[unpool_mask[i]] = i
__global__ __launch_bounds__(256) void k_mask(const int* __restrict__ mask, int* __restrict__ inv, int M) {
    int i = blockIdx.x * 256 + threadIdx.x;
    if (i < M) inv[mask[i]] = i;
}

// One block per (sample, node-range). Single edge pass:
//   - LDS histogram (deg low16 | coarse-src count high16)
//   - LDS cache of contributing in-range edges, packed (l<<18 | r)
// then block scan + one global atomic alloc, meta/normc write, self-loop entry,
// and slot assignment straight from the cache (fallback: full rescan on overflow).
// Entries written as (r, rsqrt(deg_dst)); k_coef folds in normc[r] afterwards.
__global__ __launch_bounds__(HT) void k_build(const int* __restrict__ src, const int* __restrict__ dst,
                                              const int* __restrict__ inv, int2* __restrict__ meta,
                                              float* __restrict__ normc, int2* __restrict__ vals2,
                                              int* __restrict__ gctr, int EPS) {
    __shared__ int   lh[RS];      // counts, later cursors
    __shared__ float rsd[RS];     // rsqrt(deg) per local node
    __shared__ int   sm[HT];
    __shared__ int   cache[CAP];
    __shared__ int   ncache;
    __shared__ int   gbase;
    int t = threadIdx.x;
    int b = blockIdx.x / NRNG, r = blockIdx.x % NRNG;
    int lo = r * RS;
    int nlocal = min(RS, NFINE - lo);
    int rebase = b * NFINE + lo;
    for (int j = t; j < nlocal; j += HT) lh[j] = 0;
    if (t == 0) ncache = 0;
    __syncthreads();

    const int4* s4 = (const int4*)(src + (size_t)b * EPS);
    const int4* d4 = (const int4*)(dst + (size_t)b * EPS);
    int n4 = EPS / 4;
    for (int i = t; i < n4; i += HT) {
        int4 s = s4[i], d = d4[i];
#define DO(c) { int l = d.c - rebase; if ((unsigned)l < (unsigned)nlocal) {            \
            int rr = inv[s.c];                                                          \
            atomicAdd(&lh[l], 1 + (rr >= 0 ? 65536 : 0));                               \
            if (rr >= 0) { int p = atomicAdd(&ncache, 1); if (p < CAP) cache[p] = (l << 18) | rr; } } }
        DO(x) DO(y) DO(z) DO(w)
#undef DO
    }
    __syncthreads();

    // extract per-node (m, deg, self) for 3 strided entries per thread
    int mj[3], degk[3], selfk[3];
    int psum = 0;
#pragma unroll
    for (int k = 0; k < 3; ++k) {
        int idx = t + k * HT;
        int m = 0, dg = 0, sf = 0;
        if (idx < nlocal) {
            int c = lh[idx];
            int iv = inv[rebase + idx];
            sf = (iv >= 0) ? (iv + 1) : 0;          // inv+1, 0 = no self entry
            m = (c >> 16) + (sf ? 1 : 0);
            dg = (c & 0xFFFF) + 1;
        }
        mj[k] = m; degk[k] = dg; selfk[k] = sf;
        psum += m;
    }
    sm[t] = psum; __syncthreads();
    for (int off = 1; off < HT; off <<= 1) {        // inclusive block scan
        int add = (t >= off) ? sm[t - off] : 0;
        __syncthreads();
        sm[t] += add;
        __syncthreads();
    }
    if (t == HT - 1) gbase = atomicAdd(gctr, sm[HT - 1]);
    __syncthreads();

    int run = gbase + sm[t] - psum;                 // exclusive base for this thread
#pragma unroll
    for (int k = 0; k < 3; ++k) {
        int idx = t + k * HT;
        if (idx < nlocal) {
            int gf = rebase + idx;
            float rq = rsqrtf((float)degk[k]);
            meta[gf] = make_int2(run, mj[k]);
            rsd[idx] = rq;
            int cur = run;
            if (selfk[k]) {
                int rv = selfk[k] - 1;
                normc[rv] = rq;                     // rsqrt(deg) of this coarse node
                vals2[cur] = make_int2(rv, __float_as_int(rq));
                ++cur;
            }
            lh[idx] = cur;                          // becomes cursor
            run += mj[k];
        }
    }
    __syncthreads();

    int nc = ncache;
    if (nc <= CAP) {
        for (int p = t; p < nc; p += HT) {
            int u = cache[p];
            int l = u >> 18, rr = u & 0x3FFFF;
            int pos = atomicAdd(&lh[l], 1);
            vals2[pos] = make_int2(rr, __float_as_int(rsd[l]));
        }
    } else {                                        // overflow fallback: full rescan
        for (int i = t; i < n4; i += HT) {
            int4 s = s4[i], d = d4[i];
#define DO2(c) { int l = d.c - rebase; if ((unsigned)l < (unsigned)nlocal) {           \
                int rr = inv[s.c];                                                      \
                if (rr >= 0) { int pos = atomicAdd(&lh[l], 1);                          \
                               vals2[pos] = make_int2(rr, __float_as_int(rsd[l])); } } }
            DO2(x) DO2(y) DO2(z) DO2(w)
#undef DO2
        }
    }
}

// finalize coefficients: entry.y = rsqrt(deg_dst) * normc[entry.x]
__global__ __launch_bounds__(256) void k_coef(int2* __restrict__ vals2, const float* __restrict__ normc,
                                              const int* __restrict__ gctr) {
    int j = blockIdx.x * 256 + threadIdx.x;
    if (j >= *gctr) return;
    int2 e = vals2[j];
    vals2[j] = make_int2(e.x, __float_as_int(__int_as_float(e.y) * normc[e.x]));
}

// h[M,64](bf16) = x[M,128] @ W[128,64]
__global__ __launch_bounds__(256) void k_gemm(const float* __restrict__ x, const float* __restrict__ W,
                                              __hip_bfloat16* __restrict__ h, int M) {
    __shared__ float sXT[KC][BM];
    __shared__ float sW[KC][COUT];
    int t = threadIdx.x;
    int row0 = blockIdx.x * BM;
    int tr = (t & 31) * 4;
    int tc = (t >> 5) * 8;
    float acc[4][8];
#pragma unroll
    for (int i = 0; i < 4; ++i)
#pragma unroll
        for (int j = 0; j < 8; ++j) acc[i][j] = 0.f;

    for (int k0 = 0; k0 < CIN; k0 += KC) {
        __syncthreads();
#pragma unroll
        for (int it = 0; it < 8; ++it) {
            int i = it * 256 + t;
            int row = i >> 4;
            int kq  = (i & 15) * 4;
            int gr = row0 + row;
            float4 v = (gr < M) ? *reinterpret_cast<const float4*>(&x[(size_t)gr * CIN + k0 + kq])
                                : make_float4(0.f, 0.f, 0.f, 0.f);
            sXT[kq + 0][row] = v.x;
            sXT[kq + 1][row] = v.y;
            sXT[kq + 2][row] = v.z;
            sXT[kq + 3][row] = v.w;
        }
#pragma unroll
        for (int it = 0; it < 4; ++it) {
            int i = it * 256 + t;
            int kk = i >> 4;
            int cq = (i & 15) * 4;
            *reinterpret_cast<float4*>(&sW[kk][cq]) =
                *reinterpret_cast<const float4*>(&W[(size_t)(k0 + kk) * COUT + cq]);
        }
        __syncthreads();
#pragma unroll 8
        for (int k = 0; k < KC; ++k) {
            float4 xa = *reinterpret_cast<const float4*>(&sXT[k][tr]);
            float4 wa = *reinterpret_cast<const float4*>(&sW[k][tc]);
            float4 wb = *reinterpret_cast<const float4*>(&sW[k][tc + 4]);
            float xs[4] = { xa.x, xa.y, xa.z, xa.w };
            float ws[8] = { wa.x, wa.y, wa.z, wa.w, wb.x, wb.y, wb.z, wb.w };
#pragma unroll
            for (int i = 0; i < 4; ++i)
#pragma unroll
                for (int j = 0; j < 8; ++j)
                    acc[i][j] = fmaf(xs[i], ws[j], acc[i][j]);
        }
    }
#pragma unroll
    for (int i = 0; i < 4; ++i) {
        int gr = row0 + tr + i;
        if (gr < M) {
            alignas(16) __hip_bfloat16 tmp[8];
#pragma unroll
            for (int j = 0; j < 8; ++j) tmp[j] = __float2bfloat16(acc[i][j]);
            *reinterpret_cast<float4*>(&h[(size_t)gr * COUT + tc]) = *reinterpret_cast<const float4*>(tmp);
        }
    }
}

// fused gather: wave handles 8 consecutive fine nodes, lane = channel.
// chain is meta -> (r,coef) entry -> h row; coef fully precomputed.
__global__ __launch_bounds__(256) void k_gather(const __hip_bfloat16* __restrict__ h, const int2* __restrict__ meta,
                                                const int2* __restrict__ vals2, const float* __restrict__ b,
                                                float* __restrict__ out, int N8) {
    int wid  = (blockIdx.x * 256 + threadIdx.x) >> 6;
    int lane = threadIdx.x & 63;
    if (wid >= N8) return;
    int base = wid * 8;
    float bb = b[lane];
    int bg[8], mm[8];
    float acc[8];
    int mmax = 0;
#pragma unroll
    for (int i = 0; i < 8; ++i) {
        int2 Mi = meta[base + i];
        bg[i] = Mi.x;
        mm[i] = Mi.y;
        acc[i] = 0.f;
        mmax = max(mmax, mm[i]);
    }
    for (int j = 0; j < mmax; ++j) {
        int2 e[8];
#pragma unroll
        for (int i = 0; i < 8; ++i) if (j < mm[i]) e[i] = vals2[bg[i] + j];
#pragma unroll
        for (int i = 0; i < 8; ++i)
            if (j < mm[i]) {
                const __hip_bfloat16* hp = h + ((unsigned)e[i].x << 6);
                acc[i] = fmaf(__bfloat162float(hp[lane]), __int_as_float(e[i].y), acc[i]);
            }
    }
#pragma unroll
    for (int i = 0; i < 8; ++i) {
        float o = acc[i] + bb;
        out[((size_t)base + i) * COUT + lane] = o > 0.f ? o : expm1f(o);
    }
}

extern "C" void kernel_launch(void* const* d_in, const int* in_sizes, int n_in,
                              void* d_out, int out_size, void* d_ws, size_t ws_size,
                              hipStream_t stream) {
    const float* x    = (const float*)d_in[0];
    const float* W    = (const float*)d_in[1];
    const float* b    = (const float*)d_in[2];
    const int*   edge = (const int*)d_in[3];
    const int*   mask = (const int*)d_in[4];
    const int Mx = in_sizes[0] / CIN;     // coarse rows (163968)
    const int E  = in_sizes[3] / 2;       // directed edges (3932160)
    const int N  = out_size / COUT;       // fine nodes (655360)
    const int EPS = E / BSAMP;            // edges per sample (61440)

    const int* src = edge;
    const int* dst = edge + E;

    char* ws = (char*)d_ws;
    int*   inv    = (int*)ws;      ws += (size_t)N * 4;
    int2*  meta   = (int2*)ws;     ws += (size_t)N * 8;
    int*   gctr   = (int*)ws;      ws += 256;
    float* normc  = (float*)ws;    ws += (size_t)Mx * 4;
    __hip_bfloat16* h = (__hip_bfloat16*)ws;  ws += (size_t)Mx * COUT * 2;
    int2*  vals2  = (int2*)ws;     // up to E + Mx entries (8B each)

    const int maxent = E + Mx;

    k_init  <<<(N + 255) / 256, 256, 0, stream>>>(inv, gctr, N);
    k_mask  <<<(Mx + 255) / 256, 256, 0, stream>>>(mask, inv, Mx);
    k_build <<<BSAMP * NRNG, HT, 0, stream>>>(src, dst, inv, meta, normc, vals2, gctr, EPS);
    k_coef  <<<(maxent + 255) / 256, 256, 0, stream>>>(vals2, normc, gctr);
    k_gemm  <<<(Mx + BM - 1) / BM, 256, 0, stream>>>(x, W, h, Mx);
    k_gather<<<((N / 8) * 64 + 255) / 256, 256, 0, stream>>>(h, meta, vals2, b, (float*)d_out, N / 8);
}

// Round 8
// 252.975 us; speedup vs baseline: 3.4000x; 1.0341x over previous
//
#include <hip/hip_runtime.h>
#include <hip/hip_bf16.h>
#include <math.h>

#define CIN 128
#define COUT 64
#define BM 128
#define KC 64
#define BSAMP 64      // samples in batch (fixed by problem)
#define NFINE 10242   // fine nodes per sample (fixed by problem)
#define NRNG 8        // node-ranges per sample
#define RS 1281       // ceil(NFINE / NRNG)
#define HT 512        // threads for build kernel
#define CAP 12288     // LDS edge-cache capacity (mean load 1920; overflow -> rescan)

typedef float f32x2 __attribute__((ext_vector_type(2)));

// inv[i] = -1 ; gctr = 0
__global__ __launch_bounds__(256) void k_init(int* __restrict__ inv, int* __restrict__ gctr, int N) {
    int i = blockIdx.x * 256 + threadIdx.x;
    if (i < N) inv[i] = -1;
    if (i == 0) *gctr = 0;
}

// inv[unpool_mask[i]] = i
__global__ __launch_bounds__(256) void k_mask(const int* __restrict__ mask, int* __restrict__ inv, int M) {
    int i = blockIdx.x * 256 + threadIdx.x;
    if (i < M) inv[mask[i]] = i;
}

// One block per (sample, node-range). Single edge pass:
//   - LDS histogram (deg low16 | coarse-src count high16)
//   - LDS cache of contributing in-range edges, packed (l<<18 | r)
// then block scan + one global atomic alloc, meta/normc write, self-loop entry,
// and slot assignment straight from the cache (fallback: full rescan on overflow).
// Entries written as (r, rsqrt(deg_dst)); k_coef folds in normc[r] afterwards.
__global__ __launch_bounds__(HT) void k_build(const int* __restrict__ src, const int* __restrict__ dst,
                                              const int* __restrict__ inv, int2* __restrict__ meta,
                                              float* __restrict__ normc, int2* __restrict__ vals2,
                                              int* __restrict__ gctr, int EPS) {
    __shared__ int   lh[RS];      // counts, later cursors
    __shared__ float rsd[RS];     // rsqrt(deg) per local node
    __shared__ int   sm[HT];
    __shared__ int   cache[CAP];
    __shared__ int   ncache;
    __shared__ int   gbase;
    int t = threadIdx.x;
    int b = blockIdx.x / NRNG, r = blockIdx.x % NRNG;
    int lo = r * RS;
    int nlocal = min(RS, NFINE - lo);
    int rebase = b * NFINE + lo;
    for (int j = t; j < nlocal; j += HT) lh[j] = 0;
    if (t == 0) ncache = 0;
    __syncthreads();

    const int4* s4 = (const int4*)(src + (size_t)b * EPS);
    const int4* d4 = (const int4*)(dst + (size_t)b * EPS);
    int n4 = EPS / 4;
    for (int i = t; i < n4; i += HT) {
        int4 s = s4[i], d = d4[i];
#define DO(c) { int l = d.c - rebase; if ((unsigned)l < (unsigned)nlocal) {            \
            int rr = inv[s.c];                                                          \
            atomicAdd(&lh[l], 1 + (rr >= 0 ? 65536 : 0));                               \
            if (rr >= 0) { int p = atomicAdd(&ncache, 1); if (p < CAP) cache[p] = (l << 18) | rr; } } }
        DO(x) DO(y) DO(z) DO(w)
#undef DO
    }
    __syncthreads();

    // extract per-node (m, deg, self) for 3 strided entries per thread
    int mj[3], degk[3], selfk[3];
    int psum = 0;
#pragma unroll
    for (int k = 0; k < 3; ++k) {
        int idx = t + k * HT;
        int m = 0, dg = 0, sf = 0;
        if (idx < nlocal) {
            int c = lh[idx];
            int iv = inv[rebase + idx];
            sf = (iv >= 0) ? (iv + 1) : 0;          // inv+1, 0 = no self entry
            m = (c >> 16) + (sf ? 1 : 0);
            dg = (c & 0xFFFF) + 1;
        }
        mj[k] = m; degk[k] = dg; selfk[k] = sf;
        psum += m;
    }
    sm[t] = psum; __syncthreads();
    for (int off = 1; off < HT; off <<= 1) {        // inclusive block scan
        int add = (t >= off) ? sm[t - off] : 0;
        __syncthreads();
        sm[t] += add;
        __syncthreads();
    }
    if (t == HT - 1) gbase = atomicAdd(gctr, sm[HT - 1]);
    __syncthreads();

    int run = gbase + sm[t] - psum;                 // exclusive base for this thread
#pragma unroll
    for (int k = 0; k < 3; ++k) {
        int idx = t + k * HT;
        if (idx < nlocal) {
            int gf = rebase + idx;
            float rq = rsqrtf((float)degk[k]);
            meta[gf] = make_int2(run, mj[k]);
            rsd[idx] = rq;
            int cur = run;
            if (selfk[k]) {
                int rv = selfk[k] - 1;
                normc[rv] = rq;                     // rsqrt(deg) of this coarse node
                vals2[cur] = make_int2(rv, __float_as_int(rq));
                ++cur;
            }
            lh[idx] = cur;                          // becomes cursor
            run += mj[k];
        }
    }
    __syncthreads();

    int nc = ncache;
    if (nc <= CAP) {
        for (int p = t; p < nc; p += HT) {
            int u = cache[p];
            int l = u >> 18, rr = u & 0x3FFFF;
            int pos = atomicAdd(&lh[l], 1);
            vals2[pos] = make_int2(rr, __float_as_int(rsd[l]));
        }
    } else {                                        // overflow fallback: full rescan
        for (int i = t; i < n4; i += HT) {
            int4 s = s4[i], d = d4[i];
#define DO2(c) { int l = d.c - rebase; if ((unsigned)l < (unsigned)nlocal) {           \
                int rr = inv[s.c];                                                      \
                if (rr >= 0) { int pos = atomicAdd(&lh[l], 1);                          \
                               vals2[pos] = make_int2(rr, __float_as_int(rsd[l])); } } }
            DO2(x) DO2(y) DO2(z) DO2(w)
#undef DO2
        }
    }
}

// finalize coefficients: entry.y = rsqrt(deg_dst) * normc[entry.x]
__global__ __launch_bounds__(256) void k_coef(int2* __restrict__ vals2, const float* __restrict__ normc,
                                              const int* __restrict__ gctr) {
    int j = blockIdx.x * 256 + threadIdx.x;
    if (j >= *gctr) return;
    int2 e = vals2[j];
    vals2[j] = make_int2(e.x, __float_as_int(__int_as_float(e.y) * normc[e.x]));
}

// h[M,64](bf16) = x[M,128] @ W[128,64]
__global__ __launch_bounds__(256) void k_gemm(const float* __restrict__ x, const float* __restrict__ W,
                                              __hip_bfloat16* __restrict__ h, int M) {
    __shared__ float sXT[KC][BM];
    __shared__ float sW[KC][COUT];
    int t = threadIdx.x;
    int row0 = blockIdx.x * BM;
    int tr = (t & 31) * 4;
    int tc = (t >> 5) * 8;
    float acc[4][8];
#pragma unroll
    for (int i = 0; i < 4; ++i)
#pragma unroll
        for (int j = 0; j < 8; ++j) acc[i][j] = 0.f;

    for (int k0 = 0; k0 < CIN; k0 += KC) {
        __syncthreads();
#pragma unroll
        for (int it = 0; it < 8; ++it) {
            int i = it * 256 + t;
            int row = i >> 4;
            int kq  = (i & 15) * 4;
            int gr = row0 + row;
            float4 v = (gr < M) ? *reinterpret_cast<const float4*>(&x[(size_t)gr * CIN + k0 + kq])
                                : make_float4(0.f, 0.f, 0.f, 0.f);
            sXT[kq + 0][row] = v.x;
            sXT[kq + 1][row] = v.y;
            sXT[kq + 2][row] = v.z;
            sXT[kq + 3][row] = v.w;
        }
#pragma unroll
        for (int it = 0; it < 4; ++it) {
            int i = it * 256 + t;
            int kk = i >> 4;
            int cq = (i & 15) * 4;
            *reinterpret_cast<float4*>(&sW[kk][cq]) =
                *reinterpret_cast<const float4*>(&W[(size_t)(k0 + kk) * COUT + cq]);
        }
        __syncthreads();
#pragma unroll 8
        for (int k = 0; k < KC; ++k) {
            float4 xa = *reinterpret_cast<const float4*>(&sXT[k][tr]);
            float4 wa = *reinterpret_cast<const float4*>(&sW[k][tc]);
            float4 wb = *reinterpret_cast<const float4*>(&sW[k][tc + 4]);
            float xs[4] = { xa.x, xa.y, xa.z, xa.w };
            float ws[8] = { wa.x, wa.y, wa.z, wa.w, wb.x, wb.y, wb.z, wb.w };
#pragma unroll
            for (int i = 0; i < 4; ++i)
#pragma unroll
                for (int j = 0; j < 8; ++j)
                    acc[i][j] = fmaf(xs[i], ws[j], acc[i][j]);
        }
    }
#pragma unroll
    for (int i = 0; i < 4; ++i) {
        int gr = row0 + tr + i;
        if (gr < M) {
            alignas(16) __hip_bfloat16 tmp[8];
#pragma unroll
            for (int j = 0; j < 8; ++j) tmp[j] = __float2bfloat16(acc[i][j]);
            *reinterpret_cast<float4*>(&h[(size_t)gr * COUT + tc]) = *reinterpret_cast<const float4*>(tmp);
        }
    }
}

// fused gather, half-wave node pairing: wave = 8 nodes as 4 pairs.
// lanes 0-31 serve the even node of a pair, lanes 32-63 the odd one; each lane
// owns 2 channels (one dword of the bf16 h row). bf16->f32 is a pure bit-shift.
__global__ __launch_bounds__(256) void k_gather(const __hip_bfloat16* __restrict__ h, const int2* __restrict__ meta,
                                                const int2* __restrict__ vals2, const float* __restrict__ b,
                                                float* __restrict__ out, int N8) {
    int wid  = (blockIdx.x * 256 + threadIdx.x) >> 6;
    int lane = threadIdx.x & 63;
    if (wid >= N8) return;
    int half = lane >> 5;          // which node of the pair
    int hl   = lane & 31;          // dword index within the 64-ch row
    int base = wid * 8;
    f32x2 bb = *reinterpret_cast<const f32x2*>(&b[hl * 2]);

    int bg[4], mm[4], mx[4];
    f32x2 acc[4];
    int mmax = 0;
#pragma unroll
    for (int p = 0; p < 4; ++p) {
        int2 Mi = meta[base + 2 * p + half];    // per-half broadcast load
        bg[p] = Mi.x;
        mm[p] = Mi.y;
        int mo = __shfl_xor(mm[p], 32);
        mx[p] = max(mm[p], mo);                 // wave-uniform pair max
        acc[p].x = 0.f; acc[p].y = 0.f;
        mmax = max(mmax, mx[p]);
    }
    const char* hb = (const char*)h;
    for (int j = 0; j < mmax; ++j) {
#pragma unroll
        for (int p = 0; p < 4; ++p) {
            if (j < mx[p]) {                    // wave-uniform branch
                bool act = j < mm[p];           // per-half predicate
                int2 e = act ? vals2[bg[p] + j] : make_int2(0, 0);
                unsigned hw = act ? *(const unsigned*)(hb + (((size_t)(unsigned)e.x) << 7) + hl * 4) : 0u;
                float coef = __int_as_float(e.y);
                float lo = __uint_as_float(hw << 16);
                float hi = __uint_as_float(hw & 0xFFFF0000u);
                acc[p].x = fmaf(lo, coef, acc[p].x);
                acc[p].y = fmaf(hi, coef, acc[p].y);
            }
        }
    }
#pragma unroll
    for (int p = 0; p < 4; ++p) {
        float ox = acc[p].x + bb.x;
        float oy = acc[p].y + bb.y;
        f32x2 v;
        v.x = ox > 0.f ? ox : expm1f(ox);
        v.y = oy > 0.f ? oy : expm1f(oy);
        f32x2* dst = (f32x2*)(out + ((size_t)(base + 2 * p + half)) * COUT + hl * 2);
        __builtin_nontemporal_store(v, dst);
    }
}

extern "C" void kernel_launch(void* const* d_in, const int* in_sizes, int n_in,
                              void* d_out, int out_size, void* d_ws, size_t ws_size,
                              hipStream_t stream) {
    const float* x    = (const float*)d_in[0];
    const float* W    = (const float*)d_in[1];
    const float* b    = (const float*)d_in[2];
    const int*   edge = (const int*)d_in[3];
    const int*   mask = (const int*)d_in[4];
    const int Mx = in_sizes[0] / CIN;     // coarse rows (163968)
    const int E  = in_sizes[3] / 2;       // directed edges (3932160)
    const int N  = out_size / COUT;       // fine nodes (655360)
    const int EPS = E / BSAMP;            // edges per sample (61440)

    const int* src = edge;
    const int* dst = edge + E;

    char* ws = (char*)d_ws;
    int*   inv    = (int*)ws;      ws += (size_t)N * 4;
    int2*  meta   = (int2*)ws;     ws += (size_t)N * 8;
    int*   gctr   = (int*)ws;      ws += 256;
    float* normc  = (float*)ws;    ws += (size_t)Mx * 4;
    __hip_bfloat16* h = (__hip_bfloat16*)ws;  ws += (size_t)Mx * COUT * 2;
    int2*  vals2  = (int2*)ws;     // up to E + Mx entries (8B each)

    const int maxent = E + Mx;

    k_init  <<<(N + 255) / 256, 256, 0, stream>>>(inv, gctr, N);
    k_mask  <<<(Mx + 255) / 256, 256, 0, stream>>>(mask, inv, Mx);
    k_build <<<BSAMP * NRNG, HT, 0, stream>>>(src, dst, inv, meta, normc, vals2, gctr, EPS);
    k_coef  <<<(maxent + 255) / 256, 256, 0, stream>>>(vals2, normc, gctr);
    k_gemm  <<<(Mx + BM - 1) / BM, 256, 0, stream>>>(x, W, h, Mx);
    k_gather<<<((N / 8) * 64 + 255) / 256, 256, 0, stream>>>(h, meta, vals2, b, (float*)d_out, N / 8);
}

// Round 9
// 215.519 us; speedup vs baseline: 3.9908x; 1.1738x over previous
//
#include <hip/hip_runtime.h>
#include <hip/hip_bf16.h>
#include <math.h>

#define CIN 128
#define COUT 64
#define BM 128
#define KC 64
#define BSAMP 64      // samples in batch (fixed by problem)
#define NFINE 10242   // fine nodes per sample (fixed by problem)
#define NRNG 8        // node-ranges per sample
#define RS 1281       // ceil(NFINE / NRNG)
#define HT 512        // threads for build kernel
#define CAP 12288     // LDS edge-cache capacity (mean load 1920; overflow -> rescan)
#define NCLS 17       // degree classes 0..15 and >=16

typedef float f32x2 __attribute__((ext_vector_type(2)));

// inv[i] = -1 ; gctr = 0
__global__ __launch_bounds__(256) void k_init(int* __restrict__ inv, int* __restrict__ gctr, int N) {
    int i = blockIdx.x * 256 + threadIdx.x;
    if (i < N) inv[i] = -1;
    if (i == 0) *gctr = 0;
}

// inv[unpool_mask[i]] = i
__global__ __launch_bounds__(256) void k_mask(const int* __restrict__ mask, int* __restrict__ inv, int M) {
    int i = blockIdx.x * 256 + threadIdx.x;
    if (i < M) inv[mask[i]] = i;
}

// rr[e] = inv[src[e]] + 1  (0 = src not coarse); hoists the random inv gather
// out of k_build's 8x-redundant range passes.
__global__ __launch_bounds__(256) void k_prep(const int4* __restrict__ src4, const int* __restrict__ inv,
                                              int4* __restrict__ rr4, int E4) {
    int i = blockIdx.x * 256 + threadIdx.x;
    if (i >= E4) return;
    int4 s = src4[i];
    int4 r;
    r.x = inv[s.x] + 1;
    r.y = inv[s.y] + 1;
    r.z = inv[s.z] + 1;
    r.w = inv[s.w] + 1;
    rr4[i] = r;
}

// One block per (sample, node-range). Single edge pass over (dst, rr):
//   - LDS histogram (deg low16 | coarse-src count high16)
//   - LDS cache of contributing in-range edges, packed (l<<18 | r)
// then block scan + one global atomic alloc, meta/normc/self-entry writes,
// degree-class bucketing into ord[] (uniform-m gather waves), and slot
// assignment from the cache (fallback: rescan on overflow).
// Entries written as (r, rsqrt(deg_dst)); k_coef folds in normc[r] afterwards.
__global__ __launch_bounds__(HT) void k_build(const int* __restrict__ dst, const int* __restrict__ rr,
                                              const int* __restrict__ inv, int2* __restrict__ meta,
                                              float* __restrict__ normc, int2* __restrict__ vals2,
                                              int* __restrict__ ord, int* __restrict__ gctr, int EPS) {
    __shared__ int   lh[RS];      // counts, later cursors
    __shared__ float rsd[RS];     // rsqrt(deg) per local node
    __shared__ int   sm[HT];
    __shared__ int   cache[CAP];
    __shared__ int   ccnt[NCLS];
    __shared__ int   ncache;
    __shared__ int   gbase;
    int t = threadIdx.x;
    int b = blockIdx.x / NRNG, r = blockIdx.x % NRNG;
    int lo = r * RS;
    int nlocal = min(RS, NFINE - lo);
    int rebase = b * NFINE + lo;
    for (int j = t; j < nlocal; j += HT) lh[j] = 0;
    if (t < NCLS) ccnt[t] = 0;
    if (t == 0) ncache = 0;
    __syncthreads();

    const int4* d4 = (const int4*)(dst + (size_t)b * EPS);
    const int4* r4 = (const int4*)(rr  + (size_t)b * EPS);
    int n4 = EPS / 4;
    for (int i = t; i < n4; i += HT) {
        int4 d = d4[i], rv = r4[i];
#define DO(c) { int l = d.c - rebase; if ((unsigned)l < (unsigned)nlocal) {            \
            int rc = rv.c;                                                              \
            atomicAdd(&lh[l], 1 + (rc ? 65536 : 0));                                    \
            if (rc) { int p = atomicAdd(&ncache, 1); if (p < CAP) cache[p] = (l << 18) | (rc - 1); } } }
        DO(x) DO(y) DO(z) DO(w)
#undef DO
    }
    __syncthreads();

    // extract per-node (m, deg, self, class-rank) for 3 strided entries per thread
    int mj[3], degk[3], selfk[3], cls[3], rank[3];
    int psum = 0;
#pragma unroll
    for (int k = 0; k < 3; ++k) {
        int idx = t + k * HT;
        int m = 0, dg = 0, sf = 0;
        if (idx < nlocal) {
            int c = lh[idx];
            int iv = inv[rebase + idx];
            sf = (iv >= 0) ? (iv + 1) : 0;          // inv+1, 0 = no self entry
            m = (c >> 16) + (sf ? 1 : 0);
            dg = (c & 0xFFFF) + 1;
            cls[k] = min(m, NCLS - 1);
            rank[k] = atomicAdd(&ccnt[cls[k]], 1);
        }
        mj[k] = m; degk[k] = dg; selfk[k] = sf;
        psum += m;
    }
    sm[t] = psum; __syncthreads();
    for (int off = 1; off < HT; off <<= 1) {        // inclusive block scan
        int add = (t >= off) ? sm[t - off] : 0;
        __syncthreads();
        sm[t] += add;
        __syncthreads();
    }
    if (t == HT - 1) gbase = atomicAdd(gctr, sm[HT - 1]);
    if (t == 0) {                                   // exclusive scan of class counts
        int run = 0;
#pragma unroll
        for (int c = 0; c < NCLS; ++c) { int v = ccnt[c]; ccnt[c] = run; run += v; }
    }
    __syncthreads();

    int run = gbase + sm[t] - psum;                 // exclusive base for this thread
#pragma unroll
    for (int k = 0; k < 3; ++k) {
        int idx = t + k * HT;
        if (idx < nlocal) {
            int gf = rebase + idx;
            float rq = rsqrtf((float)degk[k]);
            meta[gf] = make_int2(run, mj[k]);
            rsd[idx] = rq;
            ord[rebase + ccnt[cls[k]] + rank[k]] = gf;
            int cur = run;
            if (selfk[k]) {
                int rv = selfk[k] - 1;
                normc[rv] = rq;                     // rsqrt(deg) of this coarse node
                vals2[cur] = make_int2(rv, __float_as_int(rq));
                ++cur;
            }
            lh[idx] = cur;                          // becomes cursor
            run += mj[k];
        }
    }
    __syncthreads();

    int nc = ncache;
    if (nc <= CAP) {
        for (int p = t; p < nc; p += HT) {
            int u = cache[p];
            int l = u >> 18, rv = u & 0x3FFFF;
            int pos = atomicAdd(&lh[l], 1);
            vals2[pos] = make_int2(rv, __float_as_int(rsd[l]));
        }
    } else {                                        // overflow fallback: full rescan
        for (int i = t; i < n4; i += HT) {
            int4 d = d4[i], rv4 = r4[i];
#define DO2(c) { int l = d.c - rebase; if ((unsigned)l < (unsigned)nlocal) {           \
                int rc = rv4.c;                                                         \
                if (rc) { int pos = atomicAdd(&lh[l], 1);                               \
                          vals2[pos] = make_int2(rc - 1, __float_as_int(rsd[l])); } } }
            DO2(x) DO2(y) DO2(z) DO2(w)
#undef DO2
        }
    }
}

// finalize coefficients: entry.y = rsqrt(deg_dst) * normc[entry.x]
__global__ __launch_bounds__(256) void k_coef(int2* __restrict__ vals2, const float* __restrict__ normc,
                                              const int* __restrict__ gctr) {
    int j = blockIdx.x * 256 + threadIdx.x;
    if (j >= *gctr) return;
    int2 e = vals2[j];
    vals2[j] = make_int2(e.x, __float_as_int(__int_as_float(e.y) * normc[e.x]));
}

// h[M,64](bf16) = x[M,128] @ W[128,64]
__global__ __launch_bounds__(256) void k_gemm(const float* __restrict__ x, const float* __restrict__ W,
                                              __hip_bfloat16* __restrict__ h, int M) {
    __shared__ float sXT[KC][BM];
    __shared__ float sW[KC][COUT];
    int t = threadIdx.x;
    int row0 = blockIdx.x * BM;
    int tr = (t & 31) * 4;
    int tc = (t >> 5) * 8;
    float acc[4][8];
#pragma unroll
    for (int i = 0; i < 4; ++i)
#pragma unroll
        for (int j = 0; j < 8; ++j) acc[i][j] = 0.f;

    for (int k0 = 0; k0 < CIN; k0 += KC) {
        __syncthreads();
#pragma unroll
        for (int it = 0; it < 8; ++it) {
            int i = it * 256 + t;
            int row = i >> 4;
            int kq  = (i & 15) * 4;
            int gr = row0 + row;
            float4 v = (gr < M) ? *reinterpret_cast<const float4*>(&x[(size_t)gr * CIN + k0 + kq])
                                : make_float4(0.f, 0.f, 0.f, 0.f);
            sXT[kq + 0][row] = v.x;
            sXT[kq + 1][row] = v.y;
            sXT[kq + 2][row] = v.z;
            sXT[kq + 3][row] = v.w;
        }
#pragma unroll
        for (int it = 0; it < 4; ++it) {
            int i = it * 256 + t;
            int kk = i >> 4;
            int cq = (i & 15) * 4;
            *reinterpret_cast<float4*>(&sW[kk][cq]) =
                *reinterpret_cast<const float4*>(&W[(size_t)(k0 + kk) * COUT + cq]);
        }
        __syncthreads();
#pragma unroll 8
        for (int k = 0; k < KC; ++k) {
            float4 xa = *reinterpret_cast<const float4*>(&sXT[k][tr]);
            float4 wa = *reinterpret_cast<const float4*>(&sW[k][tc]);
            float4 wb = *reinterpret_cast<const float4*>(&sW[k][tc + 4]);
            float xs[4] = { xa.x, xa.y, xa.z, xa.w };
            float ws[8] = { wa.x, wa.y, wa.z, wa.w, wb.x, wb.y, wb.z, wb.w };
#pragma unroll
            for (int i = 0; i < 4; ++i)
#pragma unroll
                for (int j = 0; j < 8; ++j)
                    acc[i][j] = fmaf(xs[i], ws[j], acc[i][j]);
        }
    }
#pragma unroll
    for (int i = 0; i < 4; ++i) {
        int gr = row0 + tr + i;
        if (gr < M) {
            alignas(16) __hip_bfloat16 tmp[8];
#pragma unroll
            for (int j = 0; j < 8; ++j) tmp[j] = __float2bfloat16(acc[i][j]);
            *reinterpret_cast<float4*>(&h[(size_t)gr * COUT + tc]) = *reinterpret_cast<const float4*>(tmp);
        }
    }
}

// fused gather over class-sorted ord[]: wave = 8 nodes as 4 half-wave pairs;
// lane owns one dword (2 bf16 channels). Nodes in a wave share (nearly always)
// the same m -> no predication waste; m=0 waves write elu(b) and exit.
__global__ __launch_bounds__(256) void k_gather(const __hip_bfloat16* __restrict__ h, const int2* __restrict__ meta,
                                                const int2* __restrict__ vals2, const int* __restrict__ ord,
                                                const float* __restrict__ b, float* __restrict__ out, int N8) {
    int wid  = (blockIdx.x * 256 + threadIdx.x) >> 6;
    int lane = threadIdx.x & 63;
    if (wid >= N8) return;
    int half = lane >> 5;          // which node of the pair
    int hl   = lane & 31;          // dword index within the 64-ch row
    int base = wid * 8;
    f32x2 bb = *reinterpret_cast<const f32x2*>(&b[hl * 2]);

    int nid[4], bg[4], mm[4], mx[4];
    f32x2 acc[4];
    int mmax = 0;
#pragma unroll
    for (int p = 0; p < 4; ++p) {
        nid[p] = ord[base + 2 * p + half];      // per-half broadcast load
        int2 Mi = meta[nid[p]];
        bg[p] = Mi.x;
        mm[p] = Mi.y;
        int mo = __shfl_xor(mm[p], 32);
        mx[p] = max(mm[p], mo);                 // wave-uniform pair max
        acc[p].x = 0.f; acc[p].y = 0.f;
        mmax = max(mmax, mx[p]);
    }
    const char* hb = (const char*)h;
    for (int j = 0; j < mmax; ++j) {
#pragma unroll
        for (int p = 0; p < 4; ++p) {
            if (j < mx[p]) {                    // wave-uniform branch
                bool act = j < mm[p];           // per-half predicate (rarely false now)
                int2 e = act ? vals2[bg[p] + j] : make_int2(0, 0);
                unsigned hw = act ? *(const unsigned*)(hb + (((size_t)(unsigned)e.x) << 7) + hl * 4) : 0u;
                float coef = __int_as_float(e.y);
                float lof = __uint_as_float(hw << 16);
                float hif = __uint_as_float(hw & 0xFFFF0000u);
                acc[p].x = fmaf(lof, coef, acc[p].x);
                acc[p].y = fmaf(hif, coef, acc[p].y);
            }
        }
    }
#pragma unroll
    for (int p = 0; p < 4; ++p) {
        float ox = acc[p].x + bb.x;
        float oy = acc[p].y + bb.y;
        f32x2 v;
        v.x = ox > 0.f ? ox : (__expf(ox) - 1.0f);   // v_exp_f32 path, exact enough for o<=0
        v.y = oy > 0.f ? oy : (__expf(oy) - 1.0f);
        f32x2* dstp = (f32x2*)(out + ((size_t)(unsigned)nid[p]) * COUT + hl * 2);
        __builtin_nontemporal_store(v, dstp);
    }
}

extern "C" void kernel_launch(void* const* d_in, const int* in_sizes, int n_in,
                              void* d_out, int out_size, void* d_ws, size_t ws_size,
                              hipStream_t stream) {
    const float* x    = (const float*)d_in[0];
    const float* W    = (const float*)d_in[1];
    const float* b    = (const float*)d_in[2];
    const int*   edge = (const int*)d_in[3];
    const int*   mask = (const int*)d_in[4];
    const int Mx = in_sizes[0] / CIN;     // coarse rows (163968)
    const int E  = in_sizes[3] / 2;       // directed edges (3932160)
    const int N  = out_size / COUT;       // fine nodes (655360)
    const int EPS = E / BSAMP;            // edges per sample (61440)

    const int* src = edge;
    const int* dst = edge + E;

    char* ws = (char*)d_ws;
    int*   inv    = (int*)ws;      ws += (size_t)N * 4;
    int2*  meta   = (int2*)ws;     ws += (size_t)N * 8;
    int*   gctr   = (int*)ws;      ws += 256;
    float* normc  = (float*)ws;    ws += (size_t)Mx * 4;
    int*   ord    = (int*)ws;      ws += (size_t)N * 4;
    __hip_bfloat16* h = (__hip_bfloat16*)ws;
    int*   rr     = (int*)ws;      // aliases h: rr dead before k_gemm writes h
    ws += (size_t)Mx * COUT * 2;
    int2*  vals2  = (int2*)ws;     // up to E + Mx entries (8B each)

    const int maxent = E + Mx;
    const int E4 = E / 4;

    k_init  <<<(N + 255) / 256, 256, 0, stream>>>(inv, gctr, N);
    k_mask  <<<(Mx + 255) / 256, 256, 0, stream>>>(mask, inv, Mx);
    k_prep  <<<(E4 + 255) / 256, 256, 0, stream>>>((const int4*)src, inv, (int4*)rr, E4);
    k_build <<<BSAMP * NRNG, HT, 0, stream>>>(dst, rr, inv, meta, normc, vals2, ord, gctr, EPS);
    k_coef  <<<(maxent + 255) / 256, 256, 0, stream>>>(vals2, normc, gctr);
    k_gemm  <<<(Mx + BM - 1) / BM, 256, 0, stream>>>(x, W, h, Mx);
    k_gather<<<((N / 8) * 64 + 255) / 256, 256, 0, stream>>>(h, meta, vals2, ord, b, (float*)d_out, N / 8);
}

// Round 11
// 176.758 us; speedup vs baseline: 4.8660x; 1.2193x over previous
//
#include <hip/hip_runtime.h>
#include <hip/hip_bf16.h>
#include <math.h>

#define CIN 128
#define COUT 64
#define BM 128
#define KC 64
#define BSAMP 64      // samples in batch (fixed by problem)
#define NFINE 10242   // fine nodes per sample (fixed by problem)
#define NRNG 4        // node-ranges per sample
#define RS 2561       // ceil(NFINE / NRNG)
#define HT 1024       // threads for build kernel
#define CAP 9728      // LDS edge-cache capacity (mean load ~3842; overflow -> rescan)
#define NCLS 17       // degree classes 0..15 and >=16

typedef float f32x4 __attribute__((ext_vector_type(4)));

// inv[i] = -1 ; gctr = 0
__global__ __launch_bounds__(256) void k_init(int* __restrict__ inv, int* __restrict__ gctr, int N) {
    int i = blockIdx.x * 256 + threadIdx.x;
    if (i < N) inv[i] = -1;
    if (i == 0) *gctr = 0;
}

// inv[unpool_mask[i]] = i
__global__ __launch_bounds__(256) void k_mask(const int* __restrict__ mask, int* __restrict__ inv, int M) {
    int i = blockIdx.x * 256 + threadIdx.x;
    if (i < M) inv[mask[i]] = i;
}

// pk[e] = (dst_sample_local << 18) | (inv[src]+1).  dst outside the sample's
// window -> sentinel local id 0x3FFF (dropped downstream, same semantics as
// the previous range check).  One u32 per edge halves k_build's streaming.
__global__ __launch_bounds__(256) void k_prep(const int4* __restrict__ src4, const int4* __restrict__ dst4,
                                              const int* __restrict__ inv, uint4* __restrict__ pk4,
                                              int EPS, int bps) {
    int b  = blockIdx.x / bps;
    int il = (blockIdx.x % bps) * 256 + threadIdx.x;
    int n4 = EPS / 4;
    if (il >= n4) return;
    size_t i = (size_t)b * n4 + il;
    int4 s = src4[i], d = dst4[i];
    int base = b * NFINE;
    uint4 o;
#define PK(c, out) { int l = d.c - base; if ((unsigned)l >= NFINE) l = 0x3FFF;                      \
                     out = ((unsigned)l << 18) | (unsigned)(inv[s.c] + 1); }
    PK(x, o.x) PK(y, o.y) PK(z, o.z) PK(w, o.w)
#undef PK
    pk4[i] = o;
}

// One block per (sample, node-range). Single pass over pk:
//   - LDS histogram (deg low16 | coarse-src count high16)
//   - LDS cache of contributing in-range edges, packed (l<<18 | r)
// then block scan + one global atomic alloc, meta/normc/self-entry writes,
// degree-class bucketing into ord[] (uniform-m gather waves), and slot
// assignment from the cache (fallback: rescan pk on overflow).
// Entries written as (r, rsqrt(deg_dst)); k_coef folds in normc[r] afterwards.
__global__ __launch_bounds__(HT) void k_build(const uint4* __restrict__ pkall, const int* __restrict__ inv,
                                              int2* __restrict__ meta, float* __restrict__ normc,
                                              int2* __restrict__ vals2, int* __restrict__ ord,
                                              int* __restrict__ gctr, int EPS) {
    __shared__ int   lh[RS];      // counts, later cursors
    __shared__ float rsd[RS];     // rsqrt(deg) per local node
    __shared__ int   sm[HT];
    __shared__ int   cache[CAP];
    __shared__ int   ccnt[NCLS];
    __shared__ int   ncache;
    __shared__ int   gbase;
    int t = threadIdx.x;
    int b = blockIdx.x / NRNG, r = blockIdx.x % NRNG;
    int lo = r * RS;
    int nlocal = min(RS, NFINE - lo);
    int rebase = b * NFINE + lo;
    for (int j = t; j < nlocal; j += HT) lh[j] = 0;
    if (t < NCLS) ccnt[t] = 0;
    if (t == 0) ncache = 0;
    __syncthreads();

    const uint4* p4 = pkall + (size_t)b * (EPS / 4);
    int n4 = EPS / 4;
    for (int i = t; i < n4; i += HT) {
        uint4 pp = p4[i];
#define DO(c) { unsigned u = pp.c; int l = (int)(u >> 18) - lo;                        \
            if ((unsigned)l < (unsigned)nlocal) {                                       \
                int rc = (int)(u & 0x3FFFFu);                                           \
                atomicAdd(&lh[l], 1 + (rc ? 65536 : 0));                                \
                if (rc) { int p = atomicAdd(&ncache, 1);                                \
                          if (p < CAP) cache[p] = (l << 18) | (rc - 1); } } }
        DO(x) DO(y) DO(z) DO(w)
#undef DO
    }
    __syncthreads();

    // extract per-node (m, deg, self, class-rank) for 3 strided entries per thread
    int mj[3], degk[3], selfk[3], cls[3], rank[3];
    int psum = 0;
#pragma unroll
    for (int k = 0; k < 3; ++k) {
        int idx = t + k * HT;
        int m = 0, dg = 0, sf = 0;
        if (idx < nlocal) {
            int c = lh[idx];
            int iv = inv[rebase + idx];
            sf = (iv >= 0) ? (iv + 1) : 0;          // inv+1, 0 = no self entry
            m = (c >> 16) + (sf ? 1 : 0);
            dg = (c & 0xFFFF) + 1;
            cls[k] = min(m, NCLS - 1);
            rank[k] = atomicAdd(&ccnt[cls[k]], 1);
        }
        mj[k] = m; degk[k] = dg; selfk[k] = sf;
        psum += m;
    }
    sm[t] = psum; __syncthreads();
    for (int off = 1; off < HT; off <<= 1) {        // inclusive block scan
        int add = (t >= off) ? sm[t - off] : 0;
        __syncthreads();
        sm[t] += add;
        __syncthreads();
    }
    if (t == HT - 1) gbase = atomicAdd(gctr, sm[HT - 1]);
    if (t == 0) {                                   // exclusive scan of class counts
        int run = 0;
#pragma unroll
        for (int c = 0; c < NCLS; ++c) { int v = ccnt[c]; ccnt[c] = run; run += v; }
    }
    __syncthreads();

    int run = gbase + sm[t] - psum;                 // exclusive base for this thread
#pragma unroll
    for (int k = 0; k < 3; ++k) {
        int idx = t + k * HT;
        if (idx < nlocal) {
            int gf = rebase + idx;
            float rq = rsqrtf((float)degk[k]);
            meta[gf] = make_int2(run, mj[k]);
            rsd[idx] = rq;
            ord[rebase + ccnt[cls[k]] + rank[k]] = gf;
            int cur = run;
            if (selfk[k]) {
                int rv = selfk[k] - 1;
                normc[rv] = rq;                     // rsqrt(deg) of this coarse node
                vals2[cur] = make_int2(rv, __float_as_int(rq));
                ++cur;
            }
            lh[idx] = cur;                          // becomes cursor
            run += mj[k];
        }
    }
    __syncthreads();

    int nc = ncache;
    if (nc <= CAP) {
        for (int p = t; p < nc; p += HT) {
            int u = cache[p];
            int l = u >> 18, rv = u & 0x3FFFF;
            int pos = atomicAdd(&lh[l], 1);
            vals2[pos] = make_int2(rv, __float_as_int(rsd[l]));
        }
    } else {                                        // overflow fallback: full rescan
        for (int i = t; i < n4; i += HT) {
            uint4 pp = p4[i];
#define DO2(c) { unsigned u = pp.c; int l = (int)(u >> 18) - lo;                       \
                if ((unsigned)l < (unsigned)nlocal) {                                   \
                    int rc = (int)(u & 0x3FFFFu);                                       \
                    if (rc) { int pos = atomicAdd(&lh[l], 1);                           \
                              vals2[pos] = make_int2(rc - 1, __float_as_int(rsd[l])); } } }
            DO2(x) DO2(y) DO2(z) DO2(w)
#undef DO2
        }
    }
}

// finalize coefficients: entry.y = rsqrt(deg_dst) * normc[entry.x]
__global__ __launch_bounds__(256) void k_coef(int2* __restrict__ vals2, const float* __restrict__ normc,
                                              const int* __restrict__ gctr) {
    int j = blockIdx.x * 256 + threadIdx.x;
    if (j >= *gctr) return;
    int2 e = vals2[j];
    vals2[j] = make_int2(e.x, __float_as_int(__int_as_float(e.y) * normc[e.x]));
}

// h[M,64](bf16) = x[M,128] @ W[128,64]
__global__ __launch_bounds__(256) void k_gemm(const float* __restrict__ x, const float* __restrict__ W,
                                              __hip_bfloat16* __restrict__ h, int M) {
    __shared__ float sXT[KC][BM];
    __shared__ float sW[KC][COUT];
    int t = threadIdx.x;
    int row0 = blockIdx.x * BM;
    int tr = (t & 31) * 4;
    int tc = (t >> 5) * 8;
    float acc[4][8];
#pragma unroll
    for (int i = 0; i < 4; ++i)
#pragma unroll
        for (int j = 0; j < 8; ++j) acc[i][j] = 0.f;

    for (int k0 = 0; k0 < CIN; k0 += KC) {
        __syncthreads();
#pragma unroll
        for (int it = 0; it < 8; ++it) {
            int i = it * 256 + t;
            int row = i >> 4;
            int kq  = (i & 15) * 4;
            int gr = row0 + row;
            float4 v = (gr < M) ? *reinterpret_cast<const float4*>(&x[(size_t)gr * CIN + k0 + kq])
                                : make_float4(0.f, 0.f, 0.f, 0.f);
            sXT[kq + 0][row] = v.x;
            sXT[kq + 1][row] = v.y;
            sXT[kq + 2][row] = v.z;
            sXT[kq + 3][row] = v.w;
        }
#pragma unroll
        for (int it = 0; it < 4; ++it) {
            int i = it * 256 + t;
            int kk = i >> 4;
            int cq = (i & 15) * 4;
            *reinterpret_cast<float4*>(&sW[kk][cq]) =
                *reinterpret_cast<const float4*>(&W[(size_t)(k0 + kk) * COUT + cq]);
        }
        __syncthreads();
#pragma unroll 8
        for (int k = 0; k < KC; ++k) {
            float4 xa = *reinterpret_cast<const float4*>(&sXT[k][tr]);
            float4 wa = *reinterpret_cast<const float4*>(&sW[k][tc]);
            float4 wb = *reinterpret_cast<const float4*>(&sW[k][tc + 4]);
            float xs[4] = { xa.x, xa.y, xa.z, xa.w };
            float ws[8] = { wa.x, wa.y, wa.z, wa.w, wb.x, wb.y, wb.z, wb.w };
#pragma unroll
            for (int i = 0; i < 4; ++i)
#pragma unroll
                for (int j = 0; j < 8; ++j)
                    acc[i][j] = fmaf(xs[i], ws[j], acc[i][j]);
        }
    }
#pragma unroll
    for (int i = 0; i < 4; ++i) {
        int gr = row0 + tr + i;
        if (gr < M) {
            alignas(16) __hip_bfloat16 tmp[8];
#pragma unroll
            for (int j = 0; j < 8; ++j) tmp[j] = __float2bfloat16(acc[i][j]);
            *reinterpret_cast<float4*>(&h[(size_t)gr * COUT + tc]) = *reinterpret_cast<const float4*>(tmp);
        }
    }
}

// fused gather over class-sorted ord[]: wave = 16 nodes as 4 slots x 4 lane-groups.
// Group g (16 lanes) serves node ord[base+4s+g]; each lane owns 8 B of the h row
// (4 channels, uint2 load) -> one load instruction covers 4 CSR entries.
__global__ __launch_bounds__(256) void k_gather(const __hip_bfloat16* __restrict__ h, const int2* __restrict__ meta,
                                                const int2* __restrict__ vals2, const int* __restrict__ ord,
                                                const float* __restrict__ b, float* __restrict__ out, int N16) {
    int wid  = (blockIdx.x * 256 + threadIdx.x) >> 6;
    int lane = threadIdx.x & 63;
    if (wid >= N16) return;
    int g  = lane >> 4;            // lane group -> which node of the slot
    int il = lane & 15;            // uint2 index within the 128 B row
    int base = wid * 16;
    f32x4 bb = *reinterpret_cast<const f32x4*>(&b[il * 4]);

    int nid[4], bg[4], mm[4], mx[4];
    f32x4 acc[4];
    int mmax = 0;
#pragma unroll
    for (int s = 0; s < 4; ++s) {
        nid[s] = ord[base + 4 * s + g];         // group-broadcast load
        int2 Mi = meta[nid[s]];
        bg[s] = Mi.x;
        mm[s] = Mi.y;
        int m1 = max(mm[s], __shfl_xor(mm[s], 16));
        mx[s] = max(m1, __shfl_xor(m1, 32));    // wave-uniform slot max
        acc[s] = (f32x4)(0.f);
        mmax = max(mmax, mx[s]);
    }
    const char* hb = (const char*)h;
    for (int j = 0; j < mmax; ++j) {
#pragma unroll
        for (int s = 0; s < 4; ++s) {
            if (j < mx[s]) {                    // wave-uniform branch
                bool act = j < mm[s];           // uniform within a group
                int2 e = act ? vals2[bg[s] + j] : make_int2(0, 0);
                uint2 hw = act ? *(const uint2*)(hb + (((size_t)(unsigned)e.x) << 7) + il * 8)
                               : make_uint2(0u, 0u);
                float c = __int_as_float(e.y);
                acc[s].x = fmaf(__uint_as_float(hw.x << 16),         c, acc[s].x);
                acc[s].y = fmaf(__uint_as_float(hw.x & 0xFFFF0000u), c, acc[s].y);
                acc[s].z = fmaf(__uint_as_float(hw.y << 16),         c, acc[s].z);
                acc[s].w = fmaf(__uint_as_float(hw.y & 0xFFFF0000u), c, acc[s].w);
            }
        }
    }
#pragma unroll
    for (int s = 0; s < 4; ++s) {
        f32x4 v;
        v.x = acc[s].x + bb.x;
        v.y = acc[s].y + bb.y;
        v.z = acc[s].z + bb.z;
        v.w = acc[s].w + bb.w;
        v.x = v.x > 0.f ? v.x : (__expf(v.x) - 1.0f);
        v.y = v.y > 0.f ? v.y : (__expf(v.y) - 1.0f);
        v.z = v.z > 0.f ? v.z : (__expf(v.z) - 1.0f);
        v.w = v.w > 0.f ? v.w : (__expf(v.w) - 1.0f);
        f32x4* dstp = (f32x4*)(out + ((size_t)(unsigned)nid[s]) * COUT + il * 4);
        __builtin_nontemporal_store(v, dstp);
    }
}

extern "C" void kernel_launch(void* const* d_in, const int* in_sizes, int n_in,
                              void* d_out, int out_size, void* d_ws, size_t ws_size,
                              hipStream_t stream) {
    const float* x    = (const float*)d_in[0];
    const float* W    = (const float*)d_in[1];
    const float* b    = (const float*)d_in[2];
    const int*   edge = (const int*)d_in[3];
    const int*   mask = (const int*)d_in[4];
    const int Mx = in_sizes[0] / CIN;     // coarse rows (163968)
    const int E  = in_sizes[3] / 2;       // directed edges (3932160)
    const int N  = out_size / COUT;       // fine nodes (655360)
    const int EPS = E / BSAMP;            // edges per sample (61440)

    const int* src = edge;
    const int* dst = edge + E;

    char* ws = (char*)d_ws;
    int*   inv    = (int*)ws;      ws += (size_t)N * 4;
    int2*  meta   = (int2*)ws;     ws += (size_t)N * 8;
    int*   gctr   = (int*)ws;      ws += 256;
    float* normc  = (float*)ws;    ws += (size_t)Mx * 4;
    int*   ord    = (int*)ws;      ws += (size_t)N * 4;
    __hip_bfloat16* h = (__hip_bfloat16*)ws;
    unsigned* pk  = (unsigned*)ws; // aliases h: pk dead before k_gemm writes h
    ws += (size_t)Mx * COUT * 2;
    int2*  vals2  = (int2*)ws;     // up to E + Mx entries (8B each)

    const int maxent = E + Mx;
    const int bps = (EPS / 4 + 255) / 256;   // prep blocks per sample (=60)

    k_init  <<<(N + 255) / 256, 256, 0, stream>>>(inv, gctr, N);
    k_mask  <<<(Mx + 255) / 256, 256, 0, stream>>>(mask, inv, Mx);
    k_prep  <<<BSAMP * bps, 256, 0, stream>>>((const int4*)src, (const int4*)dst, inv, (uint4*)pk, EPS, bps);
    k_build <<<BSAMP * NRNG, HT, 0, stream>>>((const uint4*)pk, inv, meta, normc, vals2, ord, gctr, EPS);
    k_coef  <<<(maxent + 255) / 256, 256, 0, stream>>>(vals2, normc, gctr);
    k_gemm  <<<(Mx + BM - 1) / BM, 256, 0, stream>>>(x, W, h, Mx);
    k_gather<<<((N / 16) * 64 + 255) / 256, 256, 0, stream>>>(h, meta, vals2, ord, b, (float*)d_out, N / 16);
}